// Round 1
// baseline (1890.220 us; speedup 1.0000x reference)
//
#include <hip/hip_runtime.h>
#include <hip/hip_bf16.h>
#include <math.h>

// ---------------- problem constants ----------------
constexpr int kT    = 8192;          // tokens (4*2048)
constexpr int kD    = 1024;          // d_model
constexpr int kF    = 4096;          // d_ff
constexpr int kE    = 8;             // experts
constexpr int kN    = kT * 2;        // top-k dispatch count = 16384
constexpr int kCap  = 2048;          // ceil(1.0 * 16384 / 8)
constexpr int kECap = kE * kCap;     // 16384

typedef __attribute__((ext_vector_type(8))) short bf16x8;   // 8 bf16 (4 VGPR) MFMA A/B frag
typedef __attribute__((ext_vector_type(4))) float f32x4;    // MFMA C/D frag

// async global->LDS, 16B per lane; LDS dst must be wave-uniform (HW adds lane*16)
__device__ __forceinline__ void gload16(const __hip_bfloat16* g, __hip_bfloat16* l) {
  auto gp = (const __attribute__((address_space(1))) __hip_bfloat16*)g;
  auto lp = (__attribute__((address_space(3))) __hip_bfloat16*)l;
  __builtin_amdgcn_global_load_lds((const __attribute__((address_space(1))) void*)gp,
                                   (__attribute__((address_space(3))) void*)lp,
                                   16, 0, 0);
}

// ---------------- init: token_of = -1, imp/load = 0 ----------------
__global__ void init_kernel(int* token_of, float* imp, int* load_cnt) {
  int i = blockIdx.x * 256 + threadIdx.x;
  if (i < kECap) token_of[i] = -1;
  if (i < kE) { imp[i] = 0.f; load_cnt[i] = 0; }
}

// ---------------- transpose+convert: src [E][R][C] f32 -> dst [E][C][R] bf16 ----------------
__global__ __launch_bounds__(256)
void transpose_kernel(const float* __restrict__ src, __hip_bfloat16* __restrict__ dst,
                      int R, int C) {
  __shared__ float tile[32][33];
  const size_t mat = (size_t)R * C;
  const float* s = src + (size_t)blockIdx.z * mat;
  __hip_bfloat16* d = dst + (size_t)blockIdx.z * mat;
  int c0 = blockIdx.x * 32, r0 = blockIdx.y * 32;
  int tx = threadIdx.x, ty = threadIdx.y;
#pragma unroll
  for (int i = 0; i < 32; i += 8)
    tile[ty + i][tx] = s[(size_t)(r0 + ty + i) * C + (c0 + tx)];
  __syncthreads();
#pragma unroll
  for (int i = 0; i < 32; i += 8)
    d[(size_t)(c0 + ty + i) * R + (r0 + tx)] = __float2bfloat16(tile[tx][ty + i]);
}

// ---------------- router: fp32 logits, softmax, top-2, gates, aux stats ----------------
__global__ __launch_bounds__(256)
void router_kernel(const float* __restrict__ x, const float* __restrict__ rw,
                   const float* __restrict__ rb, int* __restrict__ e_idx,
                   float* __restrict__ gates, float* __restrict__ imp,
                   int* __restrict__ load_cnt) {
  int t = blockIdx.x * 4 + (threadIdx.x >> 6);
  int lane = threadIdx.x & 63;
  const float* xr = x + (size_t)t * kD;
  float acc[8];
#pragma unroll
  for (int e = 0; e < 8; ++e) acc[e] = 0.f;
  for (int i = 0; i < kD / 64; ++i) {
    int dd = i * 64 + lane;
    float xv = xr[dd];
    const float4* w4 = (const float4*)(rw + (size_t)dd * 8);
    float4 wa = w4[0], wb = w4[1];
    acc[0] += xv * wa.x; acc[1] += xv * wa.y; acc[2] += xv * wa.z; acc[3] += xv * wa.w;
    acc[4] += xv * wb.x; acc[5] += xv * wb.y; acc[6] += xv * wb.z; acc[7] += xv * wb.w;
  }
#pragma unroll
  for (int off = 32; off >= 1; off >>= 1) {
#pragma unroll
    for (int e = 0; e < 8; ++e) acc[e] += __shfl_xor(acc[e], off);
  }
  if (lane == 0) {
    float l[8], m = -1e30f;
#pragma unroll
    for (int e = 0; e < 8; ++e) { l[e] = acc[e] + rb[e]; m = fmaxf(m, l[e]); }
    float p[8], s = 0.f;
#pragma unroll
    for (int e = 0; e < 8; ++e) { p[e] = __expf(l[e] - m); s += p[e]; }
    float inv = 1.f / s;
#pragma unroll
    for (int e = 0; e < 8; ++e) p[e] *= inv;
    int i1 = 0;
#pragma unroll
    for (int e = 1; e < 8; ++e) if (p[e] > p[i1]) i1 = e;   // strict >: ties -> lowest idx
    int i2 = (i1 == 0) ? 1 : 0;
#pragma unroll
    for (int e = 0; e < 8; ++e) if (e != i1 && e != i2 && p[e] > p[i2]) i2 = e;
    float den = fmaxf(p[i1] + p[i2], 1e-9f);
    e_idx[2 * t] = i1; e_idx[2 * t + 1] = i2;
    gates[2 * t] = p[i1] / den; gates[2 * t + 1] = p[i2] / den;
#pragma unroll
    for (int e = 0; e < 8; ++e) atomicAdd(&imp[e], p[e]);
    atomicAdd(&load_cnt[i1], 1);
  }
}

// ---------------- stable rank within expert (counting-sort order) ----------------
__global__ __launch_bounds__(256)
void rank_kernel(const int* __restrict__ e_idx, int* __restrict__ pos) {
  int e = blockIdx.x;                 // one block per expert
  __shared__ int wave_sum[4];
  __shared__ int running;
  int tid = threadIdx.x, lane = tid & 63, wave = tid >> 6;
  if (tid == 0) running = 0;
  __syncthreads();
  for (int base = 0; base < kN; base += 256) {
    int i = base + tid;
    bool f = (e_idx[i] == e);
    unsigned long long m = __ballot(f);
    int wpre = __popcll(m & ((1ull << lane) - 1ull));
    if (lane == 0) wave_sum[wave] = __popcll(m);
    __syncthreads();
    int woff = 0;
    for (int w = 0; w < wave; ++w) woff += wave_sum[w];
    int r = running;
    if (f) pos[i] = r + woff + wpre;
    __syncthreads();
    if (tid == 0) running = r + wave_sum[0] + wave_sum[1] + wave_sum[2] + wave_sum[3];
    __syncthreads();
  }
}

// ---------------- scatter: slot assignment + inverse map ----------------
__global__ __launch_bounds__(256)
void scatter_kernel(const int* __restrict__ e_idx, const int* __restrict__ pos,
                    int* __restrict__ slot_of, int* __restrict__ token_of) {
  int i = blockIdx.x * 256 + threadIdx.x;
  if (i >= kN) return;
  int p = pos[i];
  if (p < kCap) {
    int slot = e_idx[i] * kCap + p;
    slot_of[i] = slot;
    token_of[slot] = i >> 1;
  } else {
    slot_of[i] = -1;                  // dropped (over capacity)
  }
}

// ---------------- gather: x rows -> bf16 expert buffer (zeros for unused slots) ----------------
struct __attribute__((aligned(8))) bf16x4s { __hip_bfloat16 v[4]; };

__global__ __launch_bounds__(64)
void gather_kernel(const float* __restrict__ x, const int* __restrict__ token_of,
                   __hip_bfloat16* __restrict__ buf) {
  int slot = blockIdx.x, lane = threadIdx.x;
  int t = token_of[slot];
  __hip_bfloat16* br = buf + (size_t)slot * kD;
  if (t >= 0) {
    const float* xr = x + (size_t)t * kD;
#pragma unroll
    for (int j = 0; j < 4; ++j) {
      int dd = (j * 64 + lane) * 4;
      float4 v = *(const float4*)(xr + dd);
      bf16x4s o;
      o.v[0] = __float2bfloat16(v.x); o.v[1] = __float2bfloat16(v.y);
      o.v[2] = __float2bfloat16(v.z); o.v[3] = __float2bfloat16(v.w);
      *(bf16x4s*)(br + dd) = o;
    }
  } else {
    bf16x4s z;
    z.v[0] = z.v[1] = z.v[2] = z.v[3] = __float2bfloat16(0.f);
#pragma unroll
    for (int j = 0; j < 4; ++j) *(bf16x4s*)(br + (j * 64 + lane) * 4) = z;
  }
}

// ---------------- GEMM1: h = silu(buf@w1) * (buf@w3), bf16 MFMA, fused dual-B ----------------
// per expert: M=2048(cap) x K=1024, B^T layout [4096][1024]; tile 128x128, BK=32, 4 waves
__global__ __launch_bounds__(256)
void gemm1_kernel(const __hip_bfloat16* __restrict__ Abase,
                  const __hip_bfloat16* __restrict__ W1t,
                  const __hip_bfloat16* __restrict__ W3t,
                  __hip_bfloat16* __restrict__ H) {
  constexpr int K = kD, NN = kF;
  const int e = blockIdx.z, mt = blockIdx.y, nt = blockIdx.x;
  const int tid = threadIdx.x, lane = tid & 63, wave = tid >> 6;
  const int wr = wave >> 1, wc = wave & 1;
  const int frow = lane & 15, fk = lane >> 4;

  const __hip_bfloat16* A  = Abase + (size_t)(e * kCap + mt * 128) * K;
  const __hip_bfloat16* B1 = W1t + (size_t)e * NN * K + (size_t)(nt * 128) * K;
  const __hip_bfloat16* B3 = W3t + (size_t)e * NN * K + (size_t)(nt * 128) * K;

  __shared__ __align__(16) __hip_bfloat16 As [128 * 32];
  __shared__ __align__(16) __hip_bfloat16 Bs1[128 * 32];
  __shared__ __align__(16) __hip_bfloat16 Bs3[128 * 32];

  f32x4 acc1[4][4], acc3[4][4];
#pragma unroll
  for (int m = 0; m < 4; ++m)
#pragma unroll
    for (int n = 0; n < 4; ++n) {
      acc1[m][n] = (f32x4){0.f, 0.f, 0.f, 0.f};
      acc3[m][n] = (f32x4){0.f, 0.f, 0.f, 0.f};
    }

  for (int kt = 0; kt < K / 32; ++kt) {
    __syncthreads();
    const int kb = kt * 32;
#pragma unroll
    for (int j = 0; j < 2; ++j) {
      int chunk = j * 256 + wave * 64 + lane;     // 16B chunk id: row=chunk>>2, kc=chunk&3
      int row = chunk >> 2, kc = chunk & 3;
      size_t go = (size_t)row * K + kb + kc * 8;
      int lbase = (j * 256 + wave * 64) * 8;      // wave-uniform LDS element base
      gload16(A  + go, As  + lbase);
      gload16(B1 + go, Bs1 + lbase);
      gload16(B3 + go, Bs3 + lbase);
    }
    asm volatile("s_waitcnt vmcnt(0)" ::: "memory");
    __syncthreads();

    bf16x8 af[4], b1f[4], b3f[4];
#pragma unroll
    for (int m = 0; m < 4; ++m)
      af[m] = *(const bf16x8*)&As[(wr * 64 + m * 16 + frow) * 32 + fk * 8];
#pragma unroll
    for (int n = 0; n < 4; ++n) {
      b1f[n] = *(const bf16x8*)&Bs1[(wc * 64 + n * 16 + frow) * 32 + fk * 8];
      b3f[n] = *(const bf16x8*)&Bs3[(wc * 64 + n * 16 + frow) * 32 + fk * 8];
    }
#pragma unroll
    for (int m = 0; m < 4; ++m)
#pragma unroll
      for (int n = 0; n < 4; ++n) {
        acc1[m][n] = __builtin_amdgcn_mfma_f32_16x16x32_bf16(af[m], b1f[n], acc1[m][n], 0, 0, 0);
        acc3[m][n] = __builtin_amdgcn_mfma_f32_16x16x32_bf16(af[m], b3f[n], acc3[m][n], 0, 0, 0);
      }
  }

  __hip_bfloat16* Ht = H + (size_t)(e * kCap + mt * 128) * NN + nt * 128;
#pragma unroll
  for (int m = 0; m < 4; ++m)
#pragma unroll
    for (int n = 0; n < 4; ++n)
#pragma unroll
      for (int r = 0; r < 4; ++r) {
        int row = wr * 64 + m * 16 + fk * 4 + r;  // C/D: col=lane&15, row=(lane>>4)*4+reg
        int col = wc * 64 + n * 16 + frow;
        float u = acc1[m][n][r], v = acc3[m][n][r];
        float hval = (u / (1.f + __expf(-u))) * v;
        Ht[(size_t)row * NN + col] = __float2bfloat16(hval);
      }
}

// ---------------- GEMM2: y = h @ w2 (B^T layout [1024][4096]) ----------------
__global__ __launch_bounds__(256)
void gemm2_kernel(const __hip_bfloat16* __restrict__ Hbase,
                  const __hip_bfloat16* __restrict__ W2t,
                  float* __restrict__ Y) {
  constexpr int K = kF, NN = kD;
  const int e = blockIdx.z, mt = blockIdx.y, nt = blockIdx.x;
  const int tid = threadIdx.x, lane = tid & 63, wave = tid >> 6;
  const int wr = wave >> 1, wc = wave & 1;
  const int frow = lane & 15, fk = lane >> 4;

  const __hip_bfloat16* A = Hbase + (size_t)(e * kCap + mt * 128) * K;
  const __hip_bfloat16* B = W2t + (size_t)e * NN * K + (size_t)(nt * 128) * K;

  __shared__ __align__(16) __hip_bfloat16 As[128 * 32];
  __shared__ __align__(16) __hip_bfloat16 Bs[128 * 32];

  f32x4 acc[4][4];
#pragma unroll
  for (int m = 0; m < 4; ++m)
#pragma unroll
    for (int n = 0; n < 4; ++n) acc[m][n] = (f32x4){0.f, 0.f, 0.f, 0.f};

  for (int kt = 0; kt < K / 32; ++kt) {
    __syncthreads();
    const int kb = kt * 32;
#pragma unroll
    for (int j = 0; j < 2; ++j) {
      int chunk = j * 256 + wave * 64 + lane;
      int row = chunk >> 2, kc = chunk & 3;
      size_t go = (size_t)row * K + kb + kc * 8;
      int lbase = (j * 256 + wave * 64) * 8;
      gload16(A + go, As + lbase);
      gload16(B + go, Bs + lbase);
    }
    asm volatile("s_waitcnt vmcnt(0)" ::: "memory");
    __syncthreads();

    bf16x8 af[4], bfr[4];
#pragma unroll
    for (int m = 0; m < 4; ++m)
      af[m] = *(const bf16x8*)&As[(wr * 64 + m * 16 + frow) * 32 + fk * 8];
#pragma unroll
    for (int n = 0; n < 4; ++n)
      bfr[n] = *(const bf16x8*)&Bs[(wc * 64 + n * 16 + frow) * 32 + fk * 8];
#pragma unroll
    for (int m = 0; m < 4; ++m)
#pragma unroll
      for (int n = 0; n < 4; ++n)
        acc[m][n] = __builtin_amdgcn_mfma_f32_16x16x32_bf16(af[m], bfr[n], acc[m][n], 0, 0, 0);
  }

  float* Yt = Y + (size_t)(e * kCap + mt * 128) * NN + nt * 128;
#pragma unroll
  for (int m = 0; m < 4; ++m)
#pragma unroll
    for (int n = 0; n < 4; ++n)
#pragma unroll
      for (int r = 0; r < 4; ++r) {
        int row = wr * 64 + m * 16 + fk * 4 + r;
        int col = wc * 64 + n * 16 + frow;
        Yt[(size_t)row * NN + col] = acc[m][n][r];
      }
}

// ---------------- combine: out[t] = sum_k gate * y[slot] (deterministic gather) ----------------
__global__ __launch_bounds__(256)
void combine_kernel(const float* __restrict__ Y, const int* __restrict__ slot_of,
                    const float* __restrict__ gates, float* __restrict__ out) {
  int t = blockIdx.x;
  int dd = threadIdx.x * 4;
  int s0 = slot_of[2 * t], s1 = slot_of[2 * t + 1];
  float g0 = gates[2 * t], g1 = gates[2 * t + 1];
  float4 r = {0.f, 0.f, 0.f, 0.f};
  if (s0 >= 0) {
    float4 v = *(const float4*)(Y + (size_t)s0 * kD + dd);
    r.x += g0 * v.x; r.y += g0 * v.y; r.z += g0 * v.z; r.w += g0 * v.w;
  }
  if (s1 >= 0) {
    float4 v = *(const float4*)(Y + (size_t)s1 * kD + dd);
    r.x += g1 * v.x; r.y += g1 * v.y; r.z += g1 * v.z; r.w += g1 * v.w;
  }
  *(float4*)(out + (size_t)t * kD + dd) = r;
}

// ---------------- aux loss ----------------
__global__ void finalize_kernel(const float* __restrict__ imp, const int* __restrict__ load_cnt,
                                float* __restrict__ aux_out) {
  if (threadIdx.x == 0) {
    float lb = 0.f;
    for (int e = 0; e < kE; ++e)
      lb += (imp[e] / (float)kT) * ((float)load_cnt[e] / (float)kT);
    aux_out[0] = 0.01f * lb * (float)kE;   // Z_COEF == 0
  }
}

// ---------------- host launcher ----------------
extern "C" void kernel_launch(void* const* d_in, const int* in_sizes, int n_in,
                              void* d_out, int out_size, void* d_ws, size_t ws_size,
                              hipStream_t stream) {
  (void)in_sizes; (void)n_in; (void)out_size; (void)ws_size;
  const float* x  = (const float*)d_in[0];
  const float* rw = (const float*)d_in[1];
  const float* rb = (const float*)d_in[2];
  const float* w1 = (const float*)d_in[3];
  const float* w3 = (const float*)d_in[4];
  const float* w2 = (const float*)d_in[5];
  float* out = (float*)d_out;

  char* base = (char*)d_ws;
  size_t off = 0;
  auto alloc = [&](size_t bytes) -> char* {
    char* r = base + off;
    off += (bytes + 255) & ~(size_t)255;
    return r;
  };
  __hip_bfloat16* w1t = (__hip_bfloat16*)alloc((size_t)kE * kF * kD * 2);  // [E][F][D]
  __hip_bfloat16* w3t = (__hip_bfloat16*)alloc((size_t)kE * kF * kD * 2);  // [E][F][D]
  __hip_bfloat16* w2t = (__hip_bfloat16*)alloc((size_t)kE * kD * kF * 2);  // [E][D][F]
  __hip_bfloat16* buf = (__hip_bfloat16*)alloc((size_t)kECap * kD * 2);
  __hip_bfloat16* h   = (__hip_bfloat16*)alloc((size_t)kECap * kF * 2);
  float*          y   = (float*)alloc((size_t)kECap * kD * 4);
  int*   e_idx    = (int*)alloc((size_t)kN * 4);
  float* gates    = (float*)alloc((size_t)kN * 4);
  int*   pos      = (int*)alloc((size_t)kN * 4);
  int*   slot_of  = (int*)alloc((size_t)kN * 4);
  int*   token_of = (int*)alloc((size_t)kECap * 4);
  float* imp      = (float*)alloc((size_t)kE * 4);
  int*   load_cnt = (int*)alloc((size_t)kE * 4);

  init_kernel<<<kECap / 256, 256, 0, stream>>>(token_of, imp, load_cnt);
  transpose_kernel<<<dim3(kF / 32, kD / 32, kE), dim3(32, 8, 1), 0, stream>>>(w1, w1t, kD, kF);
  transpose_kernel<<<dim3(kF / 32, kD / 32, kE), dim3(32, 8, 1), 0, stream>>>(w3, w3t, kD, kF);
  transpose_kernel<<<dim3(kD / 32, kF / 32, kE), dim3(32, 8, 1), 0, stream>>>(w2, w2t, kF, kD);
  router_kernel<<<kT / 4, 256, 0, stream>>>(x, rw, rb, e_idx, gates, imp, load_cnt);
  rank_kernel<<<kE, 256, 0, stream>>>(e_idx, pos);
  scatter_kernel<<<kN / 256, 256, 0, stream>>>(e_idx, pos, slot_of, token_of);
  gather_kernel<<<kECap, 64, 0, stream>>>(x, token_of, buf);
  gemm1_kernel<<<dim3(kF / 128, kCap / 128, kE), 256, 0, stream>>>(buf, w1t, w3t, h);
  gemm2_kernel<<<dim3(kD / 128, kCap / 128, kE), 256, 0, stream>>>(h, w2t, y);
  combine_kernel<<<kT, 256, 0, stream>>>(y, slot_of, gates, out);
  finalize_kernel<<<1, 64, 0, stream>>>(imp, load_cnt, out + (size_t)kT * kD);
}

// Round 2
// 1070.443 us; speedup vs baseline: 1.7658x; 1.7658x over previous
//
#include <hip/hip_runtime.h>
#include <hip/hip_bf16.h>
#include <math.h>

// ---------------- problem constants ----------------
constexpr int kT    = 8192;          // tokens (4*2048)
constexpr int kD    = 1024;          // d_model
constexpr int kF    = 4096;          // d_ff
constexpr int kE    = 8;             // experts
constexpr int kN    = kT * 2;        // top-k dispatch count = 16384
constexpr int kCap  = 2048;          // ceil(1.0 * 16384 / 8)
constexpr int kECap = kE * kCap;     // 16384

typedef __attribute__((ext_vector_type(8))) short bf16x8;   // 8 bf16 (4 VGPR) MFMA A/B frag
typedef __attribute__((ext_vector_type(4))) float f32x4;    // MFMA C/D frag

// async global->LDS, 16B per lane; LDS dst must be wave-uniform (HW adds lane*16)
__device__ __forceinline__ void gload16(const __hip_bfloat16* g, __hip_bfloat16* l) {
  auto gp = (const __attribute__((address_space(1))) __hip_bfloat16*)g;
  auto lp = (__attribute__((address_space(3))) __hip_bfloat16*)l;
  __builtin_amdgcn_global_load_lds((const __attribute__((address_space(1))) void*)gp,
                                   (__attribute__((address_space(3))) void*)lp,
                                   16, 0, 0);
}

// ---------------- init: token_of = -1 ----------------
__global__ void init_kernel(int* token_of) {
  int i = blockIdx.x * 256 + threadIdx.x;
  if (i < kECap) token_of[i] = -1;
}

// ---------------- transpose+convert: src [E][R][C] f32 -> dst [E][C][R] bf16 ----------------
__global__ __launch_bounds__(256)
void transpose_kernel(const float* __restrict__ src, __hip_bfloat16* __restrict__ dst,
                      int R, int C) {
  __shared__ float tile[32][33];
  const size_t mat = (size_t)R * C;
  const float* s = src + (size_t)blockIdx.z * mat;
  __hip_bfloat16* d = dst + (size_t)blockIdx.z * mat;
  int c0 = blockIdx.x * 32, r0 = blockIdx.y * 32;
  int tx = threadIdx.x, ty = threadIdx.y;
#pragma unroll
  for (int i = 0; i < 32; i += 8)
    tile[ty + i][tx] = s[(size_t)(r0 + ty + i) * C + (c0 + tx)];
  __syncthreads();
#pragma unroll
  for (int i = 0; i < 32; i += 8)
    d[(size_t)(c0 + ty + i) * R + (r0 + tx)] = __float2bfloat16(tile[tx][ty + i]);
}

// ---------------- router: fp32 logits, softmax, top-2, gates; probs -> ws (NO atomics) ----------------
__global__ __launch_bounds__(256)
void router_kernel(const float* __restrict__ x, const float* __restrict__ rw,
                   const float* __restrict__ rb, int* __restrict__ e_idx,
                   float* __restrict__ gates, float* __restrict__ probs_out) {
  int t = blockIdx.x * 4 + (threadIdx.x >> 6);
  int lane = threadIdx.x & 63;
  const float* xr = x + (size_t)t * kD;
  float acc[8];
#pragma unroll
  for (int e = 0; e < 8; ++e) acc[e] = 0.f;
  for (int i = 0; i < kD / 64; ++i) {
    int dd = i * 64 + lane;
    float xv = xr[dd];
    const float4* w4 = (const float4*)(rw + (size_t)dd * 8);
    float4 wa = w4[0], wb = w4[1];
    acc[0] += xv * wa.x; acc[1] += xv * wa.y; acc[2] += xv * wa.z; acc[3] += xv * wa.w;
    acc[4] += xv * wb.x; acc[5] += xv * wb.y; acc[6] += xv * wb.z; acc[7] += xv * wb.w;
  }
#pragma unroll
  for (int off = 32; off >= 1; off >>= 1) {
#pragma unroll
    for (int e = 0; e < 8; ++e) acc[e] += __shfl_xor(acc[e], off);
  }
  if (lane == 0) {
    float l[8], m = -1e30f;
#pragma unroll
    for (int e = 0; e < 8; ++e) { l[e] = acc[e] + rb[e]; m = fmaxf(m, l[e]); }
    float p[8], s = 0.f;
#pragma unroll
    for (int e = 0; e < 8; ++e) { p[e] = __expf(l[e] - m); s += p[e]; }
    float inv = 1.f / s;
#pragma unroll
    for (int e = 0; e < 8; ++e) p[e] *= inv;
    int i1 = 0;
#pragma unroll
    for (int e = 1; e < 8; ++e) if (p[e] > p[i1]) i1 = e;   // strict >: ties -> lowest idx
    int i2 = (i1 == 0) ? 1 : 0;
#pragma unroll
    for (int e = 0; e < 8; ++e) if (e != i1 && e != i2 && p[e] > p[i2]) i2 = e;
    float den = fmaxf(p[i1] + p[i2], 1e-9f);
    e_idx[2 * t] = i1; e_idx[2 * t + 1] = i2;
    gates[2 * t] = p[i1] / den; gates[2 * t + 1] = p[i2] / den;
    float4* po = (float4*)(probs_out + (size_t)t * 8);
    po[0] = make_float4(p[0], p[1], p[2], p[3]);
    po[1] = make_float4(p[4], p[5], p[6], p[7]);
  }
}

// ---------------- aux: importance/load reduction + aux loss (single block) ----------------
__global__ __launch_bounds__(1024)
void aux_kernel(const float* __restrict__ probs, const int* __restrict__ e_idx,
                float* __restrict__ aux_out) {
  int tid = threadIdx.x, lane = tid & 63, wave = tid >> 6;
  float imp[8];
  int cnt[8];
#pragma unroll
  for (int e = 0; e < 8; ++e) { imp[e] = 0.f; cnt[e] = 0; }
  for (int t = tid; t < kT; t += 1024) {
    const float4* p4 = (const float4*)(probs + (size_t)t * 8);
    float4 a = p4[0], b = p4[1];
    imp[0] += a.x; imp[1] += a.y; imp[2] += a.z; imp[3] += a.w;
    imp[4] += b.x; imp[5] += b.y; imp[6] += b.z; imp[7] += b.w;
    ++cnt[e_idx[2 * t] & 7];
  }
#pragma unroll
  for (int off = 32; off >= 1; off >>= 1) {
#pragma unroll
    for (int e = 0; e < 8; ++e) {
      imp[e] += __shfl_xor(imp[e], off);
      cnt[e] += __shfl_xor(cnt[e], off);
    }
  }
  __shared__ float simp[16][8];
  __shared__ int scnt[16][8];
  if (lane == 0) {
#pragma unroll
    for (int e = 0; e < 8; ++e) { simp[wave][e] = imp[e]; scnt[wave][e] = cnt[e]; }
  }
  __syncthreads();
  if (tid == 0) {
    float lb = 0.f;
    for (int e = 0; e < 8; ++e) {
      float I = 0.f; int C = 0;
      for (int w = 0; w < 16; ++w) { I += simp[w][e]; C += scnt[w][e]; }
      lb += (I / (float)kT) * ((float)C / (float)kT);
    }
    aux_out[0] = 0.01f * lb * (float)kE;   // Z_COEF == 0
  }
}

// ---------------- stable rank within expert (counting-sort order) ----------------
__global__ __launch_bounds__(256)
void rank_kernel(const int* __restrict__ e_idx, int* __restrict__ pos) {
  int e = blockIdx.x;                 // one block per expert
  __shared__ int wave_sum[4];
  __shared__ int running;
  int tid = threadIdx.x, lane = tid & 63, wave = tid >> 6;
  if (tid == 0) running = 0;
  __syncthreads();
  for (int base = 0; base < kN; base += 256) {
    int i = base + tid;
    bool f = (e_idx[i] == e);
    unsigned long long m = __ballot(f);
    int wpre = __popcll(m & ((1ull << lane) - 1ull));
    if (lane == 0) wave_sum[wave] = __popcll(m);
    __syncthreads();
    int woff = 0;
    for (int w = 0; w < wave; ++w) woff += wave_sum[w];
    int r = running;
    if (f) pos[i] = r + woff + wpre;
    __syncthreads();
    if (tid == 0) running = r + wave_sum[0] + wave_sum[1] + wave_sum[2] + wave_sum[3];
    __syncthreads();
  }
}

// ---------------- scatter: slot assignment + inverse map ----------------
__global__ __launch_bounds__(256)
void scatter_kernel(const int* __restrict__ e_idx, const int* __restrict__ pos,
                    int* __restrict__ slot_of, int* __restrict__ token_of) {
  int i = blockIdx.x * 256 + threadIdx.x;
  if (i >= kN) return;
  int p = pos[i];
  if (p < kCap) {
    int slot = e_idx[i] * kCap + p;
    slot_of[i] = slot;
    token_of[slot] = i >> 1;
  } else {
    slot_of[i] = -1;                  // dropped (over capacity)
  }
}

// ---------------- gather: x rows -> bf16 expert buffer (zeros for unused slots) ----------------
struct __attribute__((aligned(8))) bf16x4s { __hip_bfloat16 v[4]; };

__global__ __launch_bounds__(64)
void gather_kernel(const float* __restrict__ x, const int* __restrict__ token_of,
                   __hip_bfloat16* __restrict__ buf) {
  int slot = blockIdx.x, lane = threadIdx.x;
  int t = token_of[slot];
  __hip_bfloat16* br = buf + (size_t)slot * kD;
  if (t >= 0) {
    const float* xr = x + (size_t)t * kD;
#pragma unroll
    for (int j = 0; j < 4; ++j) {
      int dd = (j * 64 + lane) * 4;
      float4 v = *(const float4*)(xr + dd);
      bf16x4s o;
      o.v[0] = __float2bfloat16(v.x); o.v[1] = __float2bfloat16(v.y);
      o.v[2] = __float2bfloat16(v.z); o.v[3] = __float2bfloat16(v.w);
      *(bf16x4s*)(br + dd) = o;
    }
  } else {
    bf16x4s z;
    z.v[0] = z.v[1] = z.v[2] = z.v[3] = __float2bfloat16(0.f);
#pragma unroll
    for (int j = 0; j < 4; ++j) *(bf16x4s*)(br + (j * 64 + lane) * 4) = z;
  }
}

// ---------------- GEMM1: h = silu(buf@w1) * (buf@w3), bf16 MFMA, fused dual-B ----------------
// per expert: M=2048(cap) x K=1024, B^T layout [4096][1024]; tile 128x128, BK=32, 4 waves
__global__ __launch_bounds__(256)
void gemm1_kernel(const __hip_bfloat16* __restrict__ Abase,
                  const __hip_bfloat16* __restrict__ W1t,
                  const __hip_bfloat16* __restrict__ W3t,
                  __hip_bfloat16* __restrict__ H) {
  constexpr int K = kD, NN = kF;
  const int e = blockIdx.z, mt = blockIdx.y, nt = blockIdx.x;
  const int tid = threadIdx.x, lane = tid & 63, wave = tid >> 6;
  const int wr = wave >> 1, wc = wave & 1;
  const int frow = lane & 15, fk = lane >> 4;

  const __hip_bfloat16* A  = Abase + (size_t)(e * kCap + mt * 128) * K;
  const __hip_bfloat16* B1 = W1t + (size_t)e * NN * K + (size_t)(nt * 128) * K;
  const __hip_bfloat16* B3 = W3t + (size_t)e * NN * K + (size_t)(nt * 128) * K;

  __shared__ __align__(16) __hip_bfloat16 As [128 * 32];
  __shared__ __align__(16) __hip_bfloat16 Bs1[128 * 32];
  __shared__ __align__(16) __hip_bfloat16 Bs3[128 * 32];

  f32x4 acc1[4][4], acc3[4][4];
#pragma unroll
  for (int m = 0; m < 4; ++m)
#pragma unroll
    for (int n = 0; n < 4; ++n) {
      acc1[m][n] = (f32x4){0.f, 0.f, 0.f, 0.f};
      acc3[m][n] = (f32x4){0.f, 0.f, 0.f, 0.f};
    }

  for (int kt = 0; kt < K / 32; ++kt) {
    __syncthreads();
    const int kb = kt * 32;
#pragma unroll
    for (int j = 0; j < 2; ++j) {
      int chunk = j * 256 + wave * 64 + lane;     // 16B chunk id: row=chunk>>2, kc=chunk&3
      int row = chunk >> 2, kc = chunk & 3;
      size_t go = (size_t)row * K + kb + kc * 8;
      int lbase = (j * 256 + wave * 64) * 8;      // wave-uniform LDS element base
      gload16(A  + go, As  + lbase);
      gload16(B1 + go, Bs1 + lbase);
      gload16(B3 + go, Bs3 + lbase);
    }
    asm volatile("s_waitcnt vmcnt(0)" ::: "memory");
    __syncthreads();

    bf16x8 af[4], b1f[4], b3f[4];
#pragma unroll
    for (int m = 0; m < 4; ++m)
      af[m] = *(const bf16x8*)&As[(wr * 64 + m * 16 + frow) * 32 + fk * 8];
#pragma unroll
    for (int n = 0; n < 4; ++n) {
      b1f[n] = *(const bf16x8*)&Bs1[(wc * 64 + n * 16 + frow) * 32 + fk * 8];
      b3f[n] = *(const bf16x8*)&Bs3[(wc * 64 + n * 16 + frow) * 32 + fk * 8];
    }
#pragma unroll
    for (int m = 0; m < 4; ++m)
#pragma unroll
      for (int n = 0; n < 4; ++n) {
        acc1[m][n] = __builtin_amdgcn_mfma_f32_16x16x32_bf16(af[m], b1f[n], acc1[m][n], 0, 0, 0);
        acc3[m][n] = __builtin_amdgcn_mfma_f32_16x16x32_bf16(af[m], b3f[n], acc3[m][n], 0, 0, 0);
      }
  }

  __hip_bfloat16* Ht = H + (size_t)(e * kCap + mt * 128) * NN + nt * 128;
#pragma unroll
  for (int m = 0; m < 4; ++m)
#pragma unroll
    for (int n = 0; n < 4; ++n)
#pragma unroll
      for (int r = 0; r < 4; ++r) {
        int row = wr * 64 + m * 16 + fk * 4 + r;  // C/D: col=lane&15, row=(lane>>4)*4+reg
        int col = wc * 64 + n * 16 + frow;
        float u = acc1[m][n][r], v = acc3[m][n][r];
        float hval = (u / (1.f + __expf(-u))) * v;
        Ht[(size_t)row * NN + col] = __float2bfloat16(hval);
      }
}

// ---------------- GEMM2: y = h @ w2 (B^T layout [1024][4096]) ----------------
__global__ __launch_bounds__(256)
void gemm2_kernel(const __hip_bfloat16* __restrict__ Hbase,
                  const __hip_bfloat16* __restrict__ W2t,
                  float* __restrict__ Y) {
  constexpr int K = kF, NN = kD;
  const int e = blockIdx.z, mt = blockIdx.y, nt = blockIdx.x;
  const int tid = threadIdx.x, lane = tid & 63, wave = tid >> 6;
  const int wr = wave >> 1, wc = wave & 1;
  const int frow = lane & 15, fk = lane >> 4;

  const __hip_bfloat16* A = Hbase + (size_t)(e * kCap + mt * 128) * K;
  const __hip_bfloat16* B = W2t + (size_t)e * NN * K + (size_t)(nt * 128) * K;

  __shared__ __align__(16) __hip_bfloat16 As[128 * 32];
  __shared__ __align__(16) __hip_bfloat16 Bs[128 * 32];

  f32x4 acc[4][4];
#pragma unroll
  for (int m = 0; m < 4; ++m)
#pragma unroll
    for (int n = 0; n < 4; ++n) acc[m][n] = (f32x4){0.f, 0.f, 0.f, 0.f};

  for (int kt = 0; kt < K / 32; ++kt) {
    __syncthreads();
    const int kb = kt * 32;
#pragma unroll
    for (int j = 0; j < 2; ++j) {
      int chunk = j * 256 + wave * 64 + lane;
      int row = chunk >> 2, kc = chunk & 3;
      size_t go = (size_t)row * K + kb + kc * 8;
      int lbase = (j * 256 + wave * 64) * 8;
      gload16(A + go, As + lbase);
      gload16(B + go, Bs + lbase);
    }
    asm volatile("s_waitcnt vmcnt(0)" ::: "memory");
    __syncthreads();

    bf16x8 af[4], bfr[4];
#pragma unroll
    for (int m = 0; m < 4; ++m)
      af[m] = *(const bf16x8*)&As[(wr * 64 + m * 16 + frow) * 32 + fk * 8];
#pragma unroll
    for (int n = 0; n < 4; ++n)
      bfr[n] = *(const bf16x8*)&Bs[(wc * 64 + n * 16 + frow) * 32 + fk * 8];
#pragma unroll
    for (int m = 0; m < 4; ++m)
#pragma unroll
      for (int n = 0; n < 4; ++n)
        acc[m][n] = __builtin_amdgcn_mfma_f32_16x16x32_bf16(af[m], bfr[n], acc[m][n], 0, 0, 0);
  }

  float* Yt = Y + (size_t)(e * kCap + mt * 128) * NN + nt * 128;
#pragma unroll
  for (int m = 0; m < 4; ++m)
#pragma unroll
    for (int n = 0; n < 4; ++n)
#pragma unroll
      for (int r = 0; r < 4; ++r) {
        int row = wr * 64 + m * 16 + fk * 4 + r;
        int col = wc * 64 + n * 16 + frow;
        Yt[(size_t)row * NN + col] = acc[m][n][r];
      }
}

// ---------------- combine: out[t] = sum_k gate * y[slot] (deterministic gather) ----------------
__global__ __launch_bounds__(256)
void combine_kernel(const float* __restrict__ Y, const int* __restrict__ slot_of,
                    const float* __restrict__ gates, float* __restrict__ out) {
  int t = blockIdx.x;
  int dd = threadIdx.x * 4;
  int s0 = slot_of[2 * t], s1 = slot_of[2 * t + 1];
  float g0 = gates[2 * t], g1 = gates[2 * t + 1];
  float4 r = {0.f, 0.f, 0.f, 0.f};
  if (s0 >= 0) {
    float4 v = *(const float4*)(Y + (size_t)s0 * kD + dd);
    r.x += g0 * v.x; r.y += g0 * v.y; r.z += g0 * v.z; r.w += g0 * v.w;
  }
  if (s1 >= 0) {
    float4 v = *(const float4*)(Y + (size_t)s1 * kD + dd);
    r.x += g1 * v.x; r.y += g1 * v.y; r.z += g1 * v.z; r.w += g1 * v.w;
  }
  *(float4*)(out + (size_t)t * kD + dd) = r;
}

// ---------------- host launcher ----------------
extern "C" void kernel_launch(void* const* d_in, const int* in_sizes, int n_in,
                              void* d_out, int out_size, void* d_ws, size_t ws_size,
                              hipStream_t stream) {
  (void)in_sizes; (void)n_in; (void)out_size; (void)ws_size;
  const float* x  = (const float*)d_in[0];
  const float* rw = (const float*)d_in[1];
  const float* rb = (const float*)d_in[2];
  const float* w1 = (const float*)d_in[3];
  const float* w3 = (const float*)d_in[4];
  const float* w2 = (const float*)d_in[5];
  float* out = (float*)d_out;

  char* base = (char*)d_ws;
  size_t off = 0;
  auto alloc = [&](size_t bytes) -> char* {
    char* r = base + off;
    off += (bytes + 255) & ~(size_t)255;
    return r;
  };
  __hip_bfloat16* w1t = (__hip_bfloat16*)alloc((size_t)kE * kF * kD * 2);  // [E][F][D]
  __hip_bfloat16* w3t = (__hip_bfloat16*)alloc((size_t)kE * kF * kD * 2);  // [E][F][D]
  __hip_bfloat16* w2t = (__hip_bfloat16*)alloc((size_t)kE * kD * kF * 2);  // [E][D][F]
  __hip_bfloat16* buf = (__hip_bfloat16*)alloc((size_t)kECap * kD * 2);
  __hip_bfloat16* h   = (__hip_bfloat16*)alloc((size_t)kECap * kF * 2);
  float*          y   = (float*)alloc((size_t)kECap * kD * 4);
  int*   e_idx    = (int*)alloc((size_t)kN * 4);
  float* gates    = (float*)alloc((size_t)kN * 4);
  int*   pos      = (int*)alloc((size_t)kN * 4);
  int*   slot_of  = (int*)alloc((size_t)kN * 4);
  int*   token_of = (int*)alloc((size_t)kECap * 4);
  float* probs    = (float*)alloc((size_t)kT * 8 * 4);

  init_kernel<<<kECap / 256, 256, 0, stream>>>(token_of);
  transpose_kernel<<<dim3(kF / 32, kD / 32, kE), dim3(32, 8, 1), 0, stream>>>(w1, w1t, kD, kF);
  transpose_kernel<<<dim3(kF / 32, kD / 32, kE), dim3(32, 8, 1), 0, stream>>>(w3, w3t, kD, kF);
  transpose_kernel<<<dim3(kD / 32, kF / 32, kE), dim3(32, 8, 1), 0, stream>>>(w2, w2t, kF, kD);
  router_kernel<<<kT / 4, 256, 0, stream>>>(x, rw, rb, e_idx, gates, probs);
  aux_kernel<<<1, 1024, 0, stream>>>(probs, e_idx, out + (size_t)kT * kD);
  rank_kernel<<<kE, 256, 0, stream>>>(e_idx, pos);
  scatter_kernel<<<kN / 256, 256, 0, stream>>>(e_idx, pos, slot_of, token_of);
  gather_kernel<<<kECap, 64, 0, stream>>>(x, token_of, buf);
  gemm1_kernel<<<dim3(kF / 128, kCap / 128, kE), 256, 0, stream>>>(buf, w1t, w3t, h);
  gemm2_kernel<<<dim3(kD / 128, kCap / 128, kE), 256, 0, stream>>>(h, w2t, y);
  combine_kernel<<<kT, 256, 0, stream>>>(y, slot_of, gates, out);
  finalize: ;
  // aux already written by aux_kernel
}

// Round 3
// 794.298 us; speedup vs baseline: 2.3797x; 1.3477x over previous
//
#include <hip/hip_runtime.h>
#include <hip/hip_bf16.h>
#include <math.h>

// ---------------- problem constants ----------------
constexpr int kT    = 8192;          // tokens (4*2048)
constexpr int kD    = 1024;          // d_model
constexpr int kF    = 4096;          // d_ff
constexpr int kE    = 8;             // experts
constexpr int kN    = kT * 2;        // top-k dispatch count = 16384
constexpr int kCap  = 2048;          // ceil(1.0 * 16384 / 8)
constexpr int kECap = kE * kCap;     // 16384

typedef __attribute__((ext_vector_type(8))) short bf16x8;   // 8 bf16 (4 VGPR) MFMA A/B frag
typedef __attribute__((ext_vector_type(4))) float f32x4;    // MFMA C/D frag

// async global->LDS, 16B per lane; LDS dst must be wave-uniform (HW adds lane*16)
__device__ __forceinline__ void gload16(const __hip_bfloat16* g, __hip_bfloat16* l) {
  auto gp = (const __attribute__((address_space(1))) __hip_bfloat16*)g;
  auto lp = (__attribute__((address_space(3))) __hip_bfloat16*)l;
  __builtin_amdgcn_global_load_lds((const __attribute__((address_space(1))) void*)gp,
                                   (__attribute__((address_space(3))) void*)lp,
                                   16, 0, 0);
}

// ---------------- init: token_of = -1 ----------------
__global__ void init_kernel(int* token_of) {
  int i = blockIdx.x * 256 + threadIdx.x;
  if (i < kECap) token_of[i] = -1;
}

// ---------------- transpose+convert: src [E][R][C] f32 -> dst [E][C][R] bf16 ----------------
__global__ __launch_bounds__(256)
void transpose_kernel(const float* __restrict__ src, __hip_bfloat16* __restrict__ dst,
                      int R, int C) {
  __shared__ float tile[32][33];
  const size_t mat = (size_t)R * C;
  const float* s = src + (size_t)blockIdx.z * mat;
  __hip_bfloat16* d = dst + (size_t)blockIdx.z * mat;
  int c0 = blockIdx.x * 32, r0 = blockIdx.y * 32;
  int tx = threadIdx.x, ty = threadIdx.y;
#pragma unroll
  for (int i = 0; i < 32; i += 8)
    tile[ty + i][tx] = s[(size_t)(r0 + ty + i) * C + (c0 + tx)];
  __syncthreads();
#pragma unroll
  for (int i = 0; i < 32; i += 8)
    d[(size_t)(c0 + ty + i) * R + (r0 + tx)] = __float2bfloat16(tile[tx][ty + i]);
}

// ---------------- router: fp32 logits, softmax, top-2, gates; probs -> ws (NO atomics) ----------------
__global__ __launch_bounds__(256)
void router_kernel(const float* __restrict__ x, const float* __restrict__ rw,
                   const float* __restrict__ rb, int* __restrict__ e_idx,
                   float* __restrict__ gates, float* __restrict__ probs_out) {
  int t = blockIdx.x * 4 + (threadIdx.x >> 6);
  int lane = threadIdx.x & 63;
  const float* xr = x + (size_t)t * kD;
  float acc[8];
#pragma unroll
  for (int e = 0; e < 8; ++e) acc[e] = 0.f;
  for (int i = 0; i < kD / 64; ++i) {
    int dd = i * 64 + lane;
    float xv = xr[dd];
    const float4* w4 = (const float4*)(rw + (size_t)dd * 8);
    float4 wa = w4[0], wb = w4[1];
    acc[0] += xv * wa.x; acc[1] += xv * wa.y; acc[2] += xv * wa.z; acc[3] += xv * wa.w;
    acc[4] += xv * wb.x; acc[5] += xv * wb.y; acc[6] += xv * wb.z; acc[7] += xv * wb.w;
  }
#pragma unroll
  for (int off = 32; off >= 1; off >>= 1) {
#pragma unroll
    for (int e = 0; e < 8; ++e) acc[e] += __shfl_xor(acc[e], off);
  }
  if (lane == 0) {
    float l[8], m = -1e30f;
#pragma unroll
    for (int e = 0; e < 8; ++e) { l[e] = acc[e] + rb[e]; m = fmaxf(m, l[e]); }
    float p[8], s = 0.f;
#pragma unroll
    for (int e = 0; e < 8; ++e) { p[e] = __expf(l[e] - m); s += p[e]; }
    float inv = 1.f / s;
#pragma unroll
    for (int e = 0; e < 8; ++e) p[e] *= inv;
    int i1 = 0;
#pragma unroll
    for (int e = 1; e < 8; ++e) if (p[e] > p[i1]) i1 = e;   // strict >: ties -> lowest idx
    int i2 = (i1 == 0) ? 1 : 0;
#pragma unroll
    for (int e = 0; e < 8; ++e) if (e != i1 && e != i2 && p[e] > p[i2]) i2 = e;
    float den = fmaxf(p[i1] + p[i2], 1e-9f);
    e_idx[2 * t] = i1; e_idx[2 * t + 1] = i2;
    gates[2 * t] = p[i1] / den; gates[2 * t + 1] = p[i2] / den;
    float4* po = (float4*)(probs_out + (size_t)t * 8);
    po[0] = make_float4(p[0], p[1], p[2], p[3]);
    po[1] = make_float4(p[4], p[5], p[6], p[7]);
  }
}

// ---------------- aux: importance/load reduction + aux loss (single block) ----------------
__global__ __launch_bounds__(1024)
void aux_kernel(const float* __restrict__ probs, const int* __restrict__ e_idx,
                float* __restrict__ aux_out) {
  int tid = threadIdx.x, lane = tid & 63, wave = tid >> 6;
  float imp[8];
  int cnt[8];
#pragma unroll
  for (int e = 0; e < 8; ++e) { imp[e] = 0.f; cnt[e] = 0; }
  for (int t = tid; t < kT; t += 1024) {
    const float4* p4 = (const float4*)(probs + (size_t)t * 8);
    float4 a = p4[0], b = p4[1];
    imp[0] += a.x; imp[1] += a.y; imp[2] += a.z; imp[3] += a.w;
    imp[4] += b.x; imp[5] += b.y; imp[6] += b.z; imp[7] += b.w;
    ++cnt[e_idx[2 * t] & 7];
  }
#pragma unroll
  for (int off = 32; off >= 1; off >>= 1) {
#pragma unroll
    for (int e = 0; e < 8; ++e) {
      imp[e] += __shfl_xor(imp[e], off);
      cnt[e] += __shfl_xor(cnt[e], off);
    }
  }
  __shared__ float simp[16][8];
  __shared__ int scnt[16][8];
  if (lane == 0) {
#pragma unroll
    for (int e = 0; e < 8; ++e) { simp[wave][e] = imp[e]; scnt[wave][e] = cnt[e]; }
  }
  __syncthreads();
  if (tid == 0) {
    float lb = 0.f;
    for (int e = 0; e < 8; ++e) {
      float I = 0.f; int C = 0;
      for (int w = 0; w < 16; ++w) { I += simp[w][e]; C += scnt[w][e]; }
      lb += (I / (float)kT) * ((float)C / (float)kT);
    }
    aux_out[0] = 0.01f * lb * (float)kE;   // Z_COEF == 0
  }
}

// ---------------- stable rank within expert (counting-sort order) ----------------
__global__ __launch_bounds__(256)
void rank_kernel(const int* __restrict__ e_idx, int* __restrict__ pos) {
  int e = blockIdx.x;                 // one block per expert
  __shared__ int wave_sum[4];
  __shared__ int running;
  int tid = threadIdx.x, lane = tid & 63, wave = tid >> 6;
  if (tid == 0) running = 0;
  __syncthreads();
  for (int base = 0; base < kN; base += 256) {
    int i = base + tid;
    bool f = (e_idx[i] == e);
    unsigned long long m = __ballot(f);
    int wpre = __popcll(m & ((1ull << lane) - 1ull));
    if (lane == 0) wave_sum[wave] = __popcll(m);
    __syncthreads();
    int woff = 0;
    for (int w = 0; w < wave; ++w) woff += wave_sum[w];
    int r = running;
    if (f) pos[i] = r + woff + wpre;
    __syncthreads();
    if (tid == 0) running = r + wave_sum[0] + wave_sum[1] + wave_sum[2] + wave_sum[3];
    __syncthreads();
  }
}

// ---------------- scatter: slot assignment + inverse map ----------------
__global__ __launch_bounds__(256)
void scatter_kernel(const int* __restrict__ e_idx, const int* __restrict__ pos,
                    int* __restrict__ slot_of, int* __restrict__ token_of) {
  int i = blockIdx.x * 256 + threadIdx.x;
  if (i >= kN) return;
  int p = pos[i];
  if (p < kCap) {
    int slot = e_idx[i] * kCap + p;
    slot_of[i] = slot;
    token_of[slot] = i >> 1;
  } else {
    slot_of[i] = -1;                  // dropped (over capacity)
  }
}

// ---------------- gather: x rows -> bf16 expert buffer (zeros for unused slots) ----------------
struct __attribute__((aligned(8))) bf16x4s { __hip_bfloat16 v[4]; };

__global__ __launch_bounds__(64)
void gather_kernel(const float* __restrict__ x, const int* __restrict__ token_of,
                   __hip_bfloat16* __restrict__ buf) {
  int slot = blockIdx.x, lane = threadIdx.x;
  int t = token_of[slot];
  __hip_bfloat16* br = buf + (size_t)slot * kD;
  if (t >= 0) {
    const float* xr = x + (size_t)t * kD;
#pragma unroll
    for (int j = 0; j < 4; ++j) {
      int dd = (j * 64 + lane) * 4;
      float4 v = *(const float4*)(xr + dd);
      bf16x4s o;
      o.v[0] = __float2bfloat16(v.x); o.v[1] = __float2bfloat16(v.y);
      o.v[2] = __float2bfloat16(v.z); o.v[3] = __float2bfloat16(v.w);
      *(bf16x4s*)(br + dd) = o;
    }
  } else {
    bf16x4s z;
    z.v[0] = z.v[1] = z.v[2] = z.v[3] = __float2bfloat16(0.f);
#pragma unroll
    for (int j = 0; j < 4; ++j) *(bf16x4s*)(br + (j * 64 + lane) * 4) = z;
  }
}

// ---------------- GEMM1: h = silu(buf@w1) * (buf@w3), bf16 MFMA, fused dual-B ----------------
// 8 waves (512 thr), block tile 128x128, wave tile 64x32 dual -> 64 AGPR acc, 2 waves/SIMD
__global__ __launch_bounds__(512)
void gemm1_kernel(const __hip_bfloat16* __restrict__ Abase,
                  const __hip_bfloat16* __restrict__ W1t,
                  const __hip_bfloat16* __restrict__ W3t,
                  __hip_bfloat16* __restrict__ H) {
  constexpr int K = kD, NN = kF;
  const int e = blockIdx.z, mt = blockIdx.y, nt = blockIdx.x;
  const int tid = threadIdx.x, lane = tid & 63, wave = tid >> 6;
  const int wr = wave >> 2, wc = wave & 3;         // 2 x 4 wave grid
  const int frow = lane & 15, fk = lane >> 4;

  const __hip_bfloat16* A  = Abase + (size_t)(e * kCap + mt * 128) * K;
  const __hip_bfloat16* B1 = W1t + (size_t)e * NN * K + (size_t)(nt * 128) * K;
  const __hip_bfloat16* B3 = W3t + (size_t)e * NN * K + (size_t)(nt * 128) * K;

  __shared__ __align__(16) __hip_bfloat16 As [128 * 32];
  __shared__ __align__(16) __hip_bfloat16 Bs1[128 * 32];
  __shared__ __align__(16) __hip_bfloat16 Bs3[128 * 32];

  f32x4 acc1[4][2], acc3[4][2];
#pragma unroll
  for (int m = 0; m < 4; ++m)
#pragma unroll
    for (int n = 0; n < 2; ++n) {
      acc1[m][n] = (f32x4){0.f, 0.f, 0.f, 0.f};
      acc3[m][n] = (f32x4){0.f, 0.f, 0.f, 0.f};
    }

  // staging map: thread stages one 16B chunk per operand; chunk=tid -> row=tid>>2, kc=tid&3
  const int srow = tid >> 2, skc = tid & 3;
  const int lb = wave * 512;                       // wave-uniform LDS element base (64 lanes * 8)

  for (int kt = 0; kt < K / 32; ++kt) {
    __syncthreads();
    size_t go = (size_t)srow * K + kt * 32 + skc * 8;
    gload16(A  + go, As  + lb);
    gload16(B1 + go, Bs1 + lb);
    gload16(B3 + go, Bs3 + lb);
    asm volatile("s_waitcnt vmcnt(0)" ::: "memory");
    __syncthreads();

    bf16x8 af[4], b1f[2], b3f[2];
#pragma unroll
    for (int m = 0; m < 4; ++m)
      af[m] = *(const bf16x8*)&As[(wr * 64 + m * 16 + frow) * 32 + fk * 8];
#pragma unroll
    for (int n = 0; n < 2; ++n) {
      b1f[n] = *(const bf16x8*)&Bs1[(wc * 32 + n * 16 + frow) * 32 + fk * 8];
      b3f[n] = *(const bf16x8*)&Bs3[(wc * 32 + n * 16 + frow) * 32 + fk * 8];
    }
#pragma unroll
    for (int m = 0; m < 4; ++m)
#pragma unroll
      for (int n = 0; n < 2; ++n) {
        acc1[m][n] = __builtin_amdgcn_mfma_f32_16x16x32_bf16(af[m], b1f[n], acc1[m][n], 0, 0, 0);
        acc3[m][n] = __builtin_amdgcn_mfma_f32_16x16x32_bf16(af[m], b3f[n], acc3[m][n], 0, 0, 0);
      }
  }

  __hip_bfloat16* Ht = H + (size_t)(e * kCap + mt * 128) * NN + nt * 128;
#pragma unroll
  for (int m = 0; m < 4; ++m)
#pragma unroll
    for (int n = 0; n < 2; ++n)
#pragma unroll
      for (int r = 0; r < 4; ++r) {
        int row = wr * 64 + m * 16 + fk * 4 + r;   // C/D: col=lane&15, row=(lane>>4)*4+reg
        int col = wc * 32 + n * 16 + frow;
        float u = acc1[m][n][r], v = acc3[m][n][r];
        float hval = (u / (1.f + __expf(-u))) * v;
        Ht[(size_t)row * NN + col] = __float2bfloat16(hval);
      }
}

// ---------------- GEMM2: y = h @ w2 (B^T layout [1024][4096]) ----------------
__global__ __launch_bounds__(256)
void gemm2_kernel(const __hip_bfloat16* __restrict__ Hbase,
                  const __hip_bfloat16* __restrict__ W2t,
                  float* __restrict__ Y) {
  constexpr int K = kF, NN = kD;
  const int e = blockIdx.z, mt = blockIdx.y, nt = blockIdx.x;
  const int tid = threadIdx.x, lane = tid & 63, wave = tid >> 6;
  const int wr = wave >> 1, wc = wave & 1;
  const int frow = lane & 15, fk = lane >> 4;

  const __hip_bfloat16* A = Hbase + (size_t)(e * kCap + mt * 128) * K;
  const __hip_bfloat16* B = W2t + (size_t)e * NN * K + (size_t)(nt * 128) * K;

  __shared__ __align__(16) __hip_bfloat16 As[128 * 32];
  __shared__ __align__(16) __hip_bfloat16 Bs[128 * 32];

  f32x4 acc[4][4];
#pragma unroll
  for (int m = 0; m < 4; ++m)
#pragma unroll
    for (int n = 0; n < 4; ++n) acc[m][n] = (f32x4){0.f, 0.f, 0.f, 0.f};

  for (int kt = 0; kt < K / 32; ++kt) {
    __syncthreads();
    const int kb = kt * 32;
#pragma unroll
    for (int j = 0; j < 2; ++j) {
      int chunk = j * 256 + wave * 64 + lane;
      int row = chunk >> 2, kc = chunk & 3;
      size_t go = (size_t)row * K + kb + kc * 8;
      int lbase = (j * 256 + wave * 64) * 8;
      gload16(A + go, As + lbase);
      gload16(B + go, Bs + lbase);
    }
    asm volatile("s_waitcnt vmcnt(0)" ::: "memory");
    __syncthreads();

    bf16x8 af[4], bfr[4];
#pragma unroll
    for (int m = 0; m < 4; ++m)
      af[m] = *(const bf16x8*)&As[(wr * 64 + m * 16 + frow) * 32 + fk * 8];
#pragma unroll
    for (int n = 0; n < 4; ++n)
      bfr[n] = *(const bf16x8*)&Bs[(wc * 64 + n * 16 + frow) * 32 + fk * 8];
#pragma unroll
    for (int m = 0; m < 4; ++m)
#pragma unroll
      for (int n = 0; n < 4; ++n)
        acc[m][n] = __builtin_amdgcn_mfma_f32_16x16x32_bf16(af[m], bfr[n], acc[m][n], 0, 0, 0);
  }

  float* Yt = Y + (size_t)(e * kCap + mt * 128) * NN + nt * 128;
#pragma unroll
  for (int m = 0; m < 4; ++m)
#pragma unroll
    for (int n = 0; n < 4; ++n)
#pragma unroll
      for (int r = 0; r < 4; ++r) {
        int row = wr * 64 + m * 16 + fk * 4 + r;
        int col = wc * 64 + n * 16 + frow;
        Yt[(size_t)row * NN + col] = acc[m][n][r];
      }
}

// ---------------- combine: out[t] = sum_k gate * y[slot] (deterministic gather) ----------------
__global__ __launch_bounds__(256)
void combine_kernel(const float* __restrict__ Y, const int* __restrict__ slot_of,
                    const float* __restrict__ gates, float* __restrict__ out) {
  int t = blockIdx.x;
  int dd = threadIdx.x * 4;
  int s0 = slot_of[2 * t], s1 = slot_of[2 * t + 1];
  float g0 = gates[2 * t], g1 = gates[2 * t + 1];
  float4 r = {0.f, 0.f, 0.f, 0.f};
  if (s0 >= 0) {
    float4 v = *(const float4*)(Y + (size_t)s0 * kD + dd);
    r.x += g0 * v.x; r.y += g0 * v.y; r.z += g0 * v.z; r.w += g0 * v.w;
  }
  if (s1 >= 0) {
    float4 v = *(const float4*)(Y + (size_t)s1 * kD + dd);
    r.x += g1 * v.x; r.y += g1 * v.y; r.z += g1 * v.z; r.w += g1 * v.w;
  }
  *(float4*)(out + (size_t)t * kD + dd) = r;
}

// ---------------- host launcher ----------------
extern "C" void kernel_launch(void* const* d_in, const int* in_sizes, int n_in,
                              void* d_out, int out_size, void* d_ws, size_t ws_size,
                              hipStream_t stream) {
  (void)in_sizes; (void)n_in; (void)out_size; (void)ws_size;
  const float* x  = (const float*)d_in[0];
  const float* rw = (const float*)d_in[1];
  const float* rb = (const float*)d_in[2];
  const float* w1 = (const float*)d_in[3];
  const float* w3 = (const float*)d_in[4];
  const float* w2 = (const float*)d_in[5];
  float* out = (float*)d_out;

  char* base = (char*)d_ws;
  size_t off = 0;
  auto alloc = [&](size_t bytes) -> char* {
    char* r = base + off;
    off += (bytes + 255) & ~(size_t)255;
    return r;
  };
  __hip_bfloat16* w1t = (__hip_bfloat16*)alloc((size_t)kE * kF * kD * 2);  // [E][F][D]
  __hip_bfloat16* w3t = (__hip_bfloat16*)alloc((size_t)kE * kF * kD * 2);  // [E][F][D]
  __hip_bfloat16* w2t = (__hip_bfloat16*)alloc((size_t)kE * kD * kF * 2);  // [E][D][F]
  __hip_bfloat16* buf = (__hip_bfloat16*)alloc((size_t)kECap * kD * 2);
  __hip_bfloat16* h   = (__hip_bfloat16*)alloc((size_t)kECap * kF * 2);
  float*          y   = (float*)alloc((size_t)kECap * kD * 4);
  int*   e_idx    = (int*)alloc((size_t)kN * 4);
  float* gates    = (float*)alloc((size_t)kN * 4);
  int*   pos      = (int*)alloc((size_t)kN * 4);
  int*   slot_of  = (int*)alloc((size_t)kN * 4);
  int*   token_of = (int*)alloc((size_t)kECap * 4);
  float* probs    = (float*)alloc((size_t)kT * 8 * 4);

  init_kernel<<<kECap / 256, 256, 0, stream>>>(token_of);
  transpose_kernel<<<dim3(kF / 32, kD / 32, kE), dim3(32, 8, 1), 0, stream>>>(w1, w1t, kD, kF);
  transpose_kernel<<<dim3(kF / 32, kD / 32, kE), dim3(32, 8, 1), 0, stream>>>(w3, w3t, kD, kF);
  transpose_kernel<<<dim3(kD / 32, kF / 32, kE), dim3(32, 8, 1), 0, stream>>>(w2, w2t, kF, kD);
  router_kernel<<<kT / 4, 256, 0, stream>>>(x, rw, rb, e_idx, gates, probs);
  aux_kernel<<<1, 1024, 0, stream>>>(probs, e_idx, out + (size_t)kT * kD);
  rank_kernel<<<kE, 256, 0, stream>>>(e_idx, pos);
  scatter_kernel<<<kN / 256, 256, 0, stream>>>(e_idx, pos, slot_of, token_of);
  gather_kernel<<<kECap, 64, 0, stream>>>(x, token_of, buf);
  gemm1_kernel<<<dim3(kF / 128, kCap / 128, kE), 512, 0, stream>>>(buf, w1t, w3t, h);
  gemm2_kernel<<<dim3(kD / 128, kCap / 128, kE), 256, 0, stream>>>(h, w2t, y);
  combine_kernel<<<kT, 256, 0, stream>>>(y, slot_of, gates, out);
}

// Round 4
// 641.920 us; speedup vs baseline: 2.9446x; 1.2374x over previous
//
#include <hip/hip_runtime.h>
#include <hip/hip_bf16.h>
#include <math.h>

// ---------------- problem constants ----------------
constexpr int kT    = 8192;          // tokens (4*2048)
constexpr int kD    = 1024;          // d_model
constexpr int kF    = 4096;          // d_ff
constexpr int kE    = 8;             // experts
constexpr int kN    = kT * 2;        // top-k dispatch count = 16384
constexpr int kCap  = 2048;          // ceil(1.0 * 16384 / 8)
constexpr int kECap = kE * kCap;     // 16384

typedef __attribute__((ext_vector_type(8))) short bf16x8;   // 8 bf16 (4 VGPR) MFMA A/B frag
typedef __attribute__((ext_vector_type(4))) float f32x4;    // MFMA C/D frag

// async global->LDS, 16B per lane; LDS dst must be wave-uniform (HW adds lane*16)
__device__ __forceinline__ void gload16(const __hip_bfloat16* g, __hip_bfloat16* l) {
  auto gp = (const __attribute__((address_space(1))) __hip_bfloat16*)g;
  auto lp = (__attribute__((address_space(3))) __hip_bfloat16*)l;
  __builtin_amdgcn_global_load_lds((const __attribute__((address_space(1))) void*)gp,
                                   (__attribute__((address_space(3))) void*)lp,
                                   16, 0, 0);
}

// sync point: pin schedule, wait counted vmcnt, raw barrier (NO compiler drain), fence
#define SYNC_VM4() do { __builtin_amdgcn_sched_barrier(0); \
  asm volatile("s_waitcnt vmcnt(4)" ::: "memory"); \
  __builtin_amdgcn_s_barrier(); \
  asm volatile("" ::: "memory"); } while (0)
#define SYNC_VM0() do { __builtin_amdgcn_sched_barrier(0); \
  asm volatile("s_waitcnt vmcnt(0)" ::: "memory"); \
  __builtin_amdgcn_s_barrier(); \
  asm volatile("" ::: "memory"); } while (0)

// ---------------- init: token_of = -1 ----------------
__global__ void init_kernel(int* token_of) {
  int i = blockIdx.x * 256 + threadIdx.x;
  if (i < kECap) token_of[i] = -1;
}

// ---------------- transpose+convert: src [E][R][C] f32 -> dst [E][C][R] bf16 ----------------
__global__ __launch_bounds__(256)
void transpose_kernel(const float* __restrict__ src, __hip_bfloat16* __restrict__ dst,
                      int R, int C) {
  __shared__ float tile[32][33];
  const size_t mat = (size_t)R * C;
  const float* s = src + (size_t)blockIdx.z * mat;
  __hip_bfloat16* d = dst + (size_t)blockIdx.z * mat;
  int c0 = blockIdx.x * 32, r0 = blockIdx.y * 32;
  int tx = threadIdx.x, ty = threadIdx.y;
#pragma unroll
  for (int i = 0; i < 32; i += 8)
    tile[ty + i][tx] = s[(size_t)(r0 + ty + i) * C + (c0 + tx)];
  __syncthreads();
#pragma unroll
  for (int i = 0; i < 32; i += 8)
    d[(size_t)(c0 + ty + i) * R + (r0 + tx)] = __float2bfloat16(tile[tx][ty + i]);
}

// ---------------- router: fp32 logits, softmax, top-2, gates; probs -> ws (NO atomics) ----------------
__global__ __launch_bounds__(256)
void router_kernel(const float* __restrict__ x, const float* __restrict__ rw,
                   const float* __restrict__ rb, int* __restrict__ e_idx,
                   float* __restrict__ gates, float* __restrict__ probs_out) {
  int t = blockIdx.x * 4 + (threadIdx.x >> 6);
  int lane = threadIdx.x & 63;
  const float* xr = x + (size_t)t * kD;
  float acc[8];
#pragma unroll
  for (int e = 0; e < 8; ++e) acc[e] = 0.f;
  for (int i = 0; i < kD / 64; ++i) {
    int dd = i * 64 + lane;
    float xv = xr[dd];
    const float4* w4 = (const float4*)(rw + (size_t)dd * 8);
    float4 wa = w4[0], wb = w4[1];
    acc[0] += xv * wa.x; acc[1] += xv * wa.y; acc[2] += xv * wa.z; acc[3] += xv * wa.w;
    acc[4] += xv * wb.x; acc[5] += xv * wb.y; acc[6] += xv * wb.z; acc[7] += xv * wb.w;
  }
#pragma unroll
  for (int off = 32; off >= 1; off >>= 1) {
#pragma unroll
    for (int e = 0; e < 8; ++e) acc[e] += __shfl_xor(acc[e], off);
  }
  if (lane == 0) {
    float l[8], m = -1e30f;
#pragma unroll
    for (int e = 0; e < 8; ++e) { l[e] = acc[e] + rb[e]; m = fmaxf(m, l[e]); }
    float p[8], s = 0.f;
#pragma unroll
    for (int e = 0; e < 8; ++e) { p[e] = __expf(l[e] - m); s += p[e]; }
    float inv = 1.f / s;
#pragma unroll
    for (int e = 0; e < 8; ++e) p[e] *= inv;
    int i1 = 0;
#pragma unroll
    for (int e = 1; e < 8; ++e) if (p[e] > p[i1]) i1 = e;   // strict >: ties -> lowest idx
    int i2 = (i1 == 0) ? 1 : 0;
#pragma unroll
    for (int e = 0; e < 8; ++e) if (e != i1 && e != i2 && p[e] > p[i2]) i2 = e;
    float den = fmaxf(p[i1] + p[i2], 1e-9f);
    e_idx[2 * t] = i1; e_idx[2 * t + 1] = i2;
    gates[2 * t] = p[i1] / den; gates[2 * t + 1] = p[i2] / den;
    float4* po = (float4*)(probs_out + (size_t)t * 8);
    po[0] = make_float4(p[0], p[1], p[2], p[3]);
    po[1] = make_float4(p[4], p[5], p[6], p[7]);
  }
}

// ---------------- aux: importance/load reduction + aux loss (single block) ----------------
__global__ __launch_bounds__(1024)
void aux_kernel(const float* __restrict__ probs, const int* __restrict__ e_idx,
                float* __restrict__ aux_out) {
  int tid = threadIdx.x, lane = tid & 63, wave = tid >> 6;
  float imp[8];
  int cnt[8];
#pragma unroll
  for (int e = 0; e < 8; ++e) { imp[e] = 0.f; cnt[e] = 0; }
  for (int t = tid; t < kT; t += 1024) {
    const float4* p4 = (const float4*)(probs + (size_t)t * 8);
    float4 a = p4[0], b = p4[1];
    imp[0] += a.x; imp[1] += a.y; imp[2] += a.z; imp[3] += a.w;
    imp[4] += b.x; imp[5] += b.y; imp[6] += b.z; imp[7] += b.w;
    ++cnt[e_idx[2 * t] & 7];
  }
#pragma unroll
  for (int off = 32; off >= 1; off >>= 1) {
#pragma unroll
    for (int e = 0; e < 8; ++e) {
      imp[e] += __shfl_xor(imp[e], off);
      cnt[e] += __shfl_xor(cnt[e], off);
    }
  }
  __shared__ float simp[16][8];
  __shared__ int scnt[16][8];
  if (lane == 0) {
#pragma unroll
    for (int e = 0; e < 8; ++e) { simp[wave][e] = imp[e]; scnt[wave][e] = cnt[e]; }
  }
  __syncthreads();
  if (tid == 0) {
    float lb = 0.f;
    for (int e = 0; e < 8; ++e) {
      float I = 0.f; int C = 0;
      for (int w = 0; w < 16; ++w) { I += simp[w][e]; C += scnt[w][e]; }
      lb += (I / (float)kT) * ((float)C / (float)kT);
    }
    aux_out[0] = 0.01f * lb * (float)kE;   // Z_COEF == 0
  }
}

// ---------------- stable rank within expert (counting-sort order) ----------------
__global__ __launch_bounds__(256)
void rank_kernel(const int* __restrict__ e_idx, int* __restrict__ pos) {
  int e = blockIdx.x;                 // one block per expert
  __shared__ int wave_sum[4];
  __shared__ int running;
  int tid = threadIdx.x, lane = tid & 63, wave = tid >> 6;
  if (tid == 0) running = 0;
  __syncthreads();
  for (int base = 0; base < kN; base += 256) {
    int i = base + tid;
    bool f = (e_idx[i] == e);
    unsigned long long m = __ballot(f);
    int wpre = __popcll(m & ((1ull << lane) - 1ull));
    if (lane == 0) wave_sum[wave] = __popcll(m);
    __syncthreads();
    int woff = 0;
    for (int w = 0; w < wave; ++w) woff += wave_sum[w];
    int r = running;
    if (f) pos[i] = r + woff + wpre;
    __syncthreads();
    if (tid == 0) running = r + wave_sum[0] + wave_sum[1] + wave_sum[2] + wave_sum[3];
    __syncthreads();
  }
}

// ---------------- scatter: slot assignment + inverse map ----------------
__global__ __launch_bounds__(256)
void scatter_kernel(const int* __restrict__ e_idx, const int* __restrict__ pos,
                    int* __restrict__ slot_of, int* __restrict__ token_of) {
  int i = blockIdx.x * 256 + threadIdx.x;
  if (i >= kN) return;
  int p = pos[i];
  if (p < kCap) {
    int slot = e_idx[i] * kCap + p;
    slot_of[i] = slot;
    token_of[slot] = i >> 1;
  } else {
    slot_of[i] = -1;                  // dropped (over capacity)
  }
}

// ---------------- gather: x rows -> bf16 expert buffer (zeros for unused slots) ----------------
struct __attribute__((aligned(8))) bf16x4s { __hip_bfloat16 v[4]; };

__global__ __launch_bounds__(64)
void gather_kernel(const float* __restrict__ x, const int* __restrict__ token_of,
                   __hip_bfloat16* __restrict__ buf) {
  int slot = blockIdx.x, lane = threadIdx.x;
  int t = token_of[slot];
  __hip_bfloat16* br = buf + (size_t)slot * kD;
  if (t >= 0) {
    const float* xr = x + (size_t)t * kD;
#pragma unroll
    for (int j = 0; j < 4; ++j) {
      int dd = (j * 64 + lane) * 4;
      float4 v = *(const float4*)(xr + dd);
      bf16x4s o;
      o.v[0] = __float2bfloat16(v.x); o.v[1] = __float2bfloat16(v.y);
      o.v[2] = __float2bfloat16(v.z); o.v[3] = __float2bfloat16(v.w);
      *(bf16x4s*)(br + dd) = o;
    }
  } else {
    bf16x4s z;
    z.v[0] = z.v[1] = z.v[2] = z.v[3] = __float2bfloat16(0.f);
#pragma unroll
    for (int j = 0; j < 4; ++j) *(bf16x4s*)(br + (j * 64 + lane) * 4) = z;
  }
}

// ================= GEMM1: h = silu(buf@w1) * (buf@w3) =================
// 256M x 128F tile, BK=64, 8 waves (4M x 2N), wave = 64x64 dual (u,v)
// LDS [2 buf][ A[2 khalf][256][32] | B[2 khalf][256][32] ] = 128 KB, 4-phase ring, vmcnt(4)
__global__ __launch_bounds__(512, 2)
void gemm1_kernel(const __hip_bfloat16* __restrict__ Abase,
                  const __hip_bfloat16* __restrict__ W1t,
                  const __hip_bfloat16* __restrict__ W3t,
                  __hip_bfloat16* __restrict__ H) {
  constexpr int K = kD;             // 1024
  constexpr int NT = K / 64;        // 16 K-tiles
  const int e = blockIdx.z, mt = blockIdx.y, ft = blockIdx.x;   // ft: 128 f-cols
  const int tid = threadIdx.x, lane = tid & 63, wave = tid >> 6;
  const int wr = wave >> 1, wc = wave & 1;   // 4M x 2N
  const int frow = lane & 15, fk = lane >> 4;

  const __hip_bfloat16* A  = Abase + (size_t)(e * kCap + mt * 256) * K;
  const __hip_bfloat16* B1 = W1t + ((size_t)e * kF + ft * 128) * K;
  const __hip_bfloat16* B3 = W3t + ((size_t)e * kF + ft * 128) * K;

  extern __shared__ __hip_bfloat16 lds[];   // 65536 elems = 128 KB

  f32x4 accU[4][4], accV[4][4];
#pragma unroll
  for (int m = 0; m < 4; ++m)
#pragma unroll
    for (int n = 0; n < 4; ++n) {
      accU[m][n] = (f32x4){0.f, 0.f, 0.f, 0.f};
      accV[m][n] = (f32x4){0.f, 0.f, 0.f, 0.f};
    }

  // stage one half-tile (16KB = 2 x gload16/thread). A rows: 256 of A-tile.
  auto stageA = [&](int t, int h, int b) {
#pragma unroll
    for (int j = 0; j < 2; ++j) {
      int c = j * 512 + wave * 64 + lane;                       // 16B chunk id
      const __hip_bfloat16* g = A + (size_t)(c >> 2) * K + t * 64 + h * 32 + (c & 3) * 8;
      gload16(g, &lds[b * 32768 + h * 8192 + (j * 512 + wave * 64) * 8]);
    }
  };
  // B rows 0-127 = w1 f-rows, 128-255 = w3 f-rows
  auto stageB = [&](int t, int h, int b) {
    {
      int c = wave * 64 + lane;
      const __hip_bfloat16* g = B1 + (size_t)(c >> 2) * K + t * 64 + h * 32 + (c & 3) * 8;
      gload16(g, &lds[b * 32768 + 16384 + h * 8192 + (wave * 64) * 8]);
    }
    {
      int c = wave * 64 + lane;
      const __hip_bfloat16* g = B3 + (size_t)(c >> 2) * K + t * 64 + h * 32 + (c & 3) * 8;
      gload16(g, &lds[b * 32768 + 16384 + h * 8192 + 4096 + (wave * 64) * 8]);
    }
  };
  auto ldA = [&](int h, int b, bf16x8 (&af)[4]) {
#pragma unroll
    for (int m = 0; m < 4; ++m) {
      int row = wr * 64 + m * 16 + frow;
      af[m] = *(const bf16x8*)&lds[b * 32768 + h * 8192 + row * 32 + fk * 8];
    }
  };
  auto ldB = [&](int h, int b, int roff, bf16x8 (&bf)[4]) {
#pragma unroll
    for (int n = 0; n < 4; ++n) {
      int row = roff + wc * 64 + n * 16 + frow;
      bf[n] = *(const bf16x8*)&lds[b * 32768 + 16384 + h * 8192 + row * 32 + fk * 8];
    }
  };
  auto mm = [&](bf16x8 (&a)[4], bf16x8 (&bb)[4], f32x4 (&acc)[4][4]) {
    __builtin_amdgcn_s_setprio(1);
#pragma unroll
    for (int m = 0; m < 4; ++m)
#pragma unroll
      for (int n = 0; n < 4; ++n)
        acc[m][n] = __builtin_amdgcn_mfma_f32_16x16x32_bf16(a[m], bb[n], acc[m][n], 0, 0, 0);
    __builtin_amdgcn_s_setprio(0);
    __builtin_amdgcn_sched_barrier(0);
  };

  // prologue: tile 0 (issue order A0,B0,A1,B1 -> vmcnt(4) at sync-1 covers A0,B0)
  stageA(0, 0, 0); stageB(0, 0, 0); stageA(0, 1, 0); stageB(0, 1, 0);

  for (int t = 0; t < NT - 1; ++t) {
    const int b = t & 1, nb = b ^ 1;
    SYNC_VM4();                                  // k0 of t landed (k1 stages in flight)
    bf16x8 a0[4], bu[4], bv[4];
    ldA(0, b, a0); ldB(0, b, 0, bu);
    stageA(t + 1, 0, nb);                        // ph1 prefetch
    mm(a0, bu, accU);
    ldB(0, b, 128, bv);
    stageB(t + 1, 0, nb);                        // ph2 prefetch
    mm(a0, bv, accV);
    SYNC_VM4();                                  // k1 of t landed (k0(t+1) in flight)
    bf16x8 a1[4];
    ldA(1, b, a1); ldB(1, b, 0, bu);
    stageA(t + 1, 1, nb);                        // ph3 prefetch
    mm(a1, bu, accU);
    ldB(1, b, 128, bv);
    stageB(t + 1, 1, nb);                        // ph4 prefetch
    mm(a1, bv, accV);
  }
  {                                              // peeled last tile: no prefetch
    const int b = (NT - 1) & 1;
    SYNC_VM4();
    bf16x8 a0[4], bu[4], bv[4];
    ldA(0, b, a0); ldB(0, b, 0, bu);
    mm(a0, bu, accU);
    ldB(0, b, 128, bv);
    mm(a0, bv, accV);
    SYNC_VM0();
    bf16x8 a1[4];
    ldA(1, b, a1); ldB(1, b, 0, bu);
    mm(a1, bu, accU);
    ldB(1, b, 128, bv);
    mm(a1, bv, accV);
  }

  // epilogue: h = silu(u) * v
  __hip_bfloat16* Ht = H + (size_t)(e * kCap + mt * 256) * kF + ft * 128;
#pragma unroll
  for (int m = 0; m < 4; ++m)
#pragma unroll
    for (int n = 0; n < 4; ++n)
#pragma unroll
      for (int r = 0; r < 4; ++r) {
        int row = wr * 64 + m * 16 + fk * 4 + r;   // C/D: col=lane&15, row=(lane>>4)*4+reg
        int col = wc * 64 + n * 16 + frow;
        float u = accU[m][n][r], v = accV[m][n][r];
        float hval = (u / (1.f + __expf(-u))) * v;
        Ht[(size_t)row * kF + col] = __float2bfloat16(hval);
      }
}

// ================= GEMM2: y = h @ w2 =================
// 256M x 256N tile, BK=64, 8 waves (2M x 4N), wave = 128x64; same 4-phase ring
__global__ __launch_bounds__(512, 2)
void gemm2_kernel(const __hip_bfloat16* __restrict__ Hbase,
                  const __hip_bfloat16* __restrict__ W2t,
                  float* __restrict__ Y) {
  constexpr int K = kF;             // 4096
  constexpr int NT = K / 64;        // 64 K-tiles
  const int e = blockIdx.z, mt = blockIdx.y, nt = blockIdx.x;
  const int tid = threadIdx.x, lane = tid & 63, wave = tid >> 6;
  const int wr = wave >> 2, wc = wave & 3;   // 2M x 4N
  const int frow = lane & 15, fk = lane >> 4;

  const __hip_bfloat16* A = Hbase + (size_t)(e * kCap + mt * 256) * K;
  const __hip_bfloat16* B = W2t + ((size_t)e * kD + nt * 256) * K;

  extern __shared__ __hip_bfloat16 lds[];

  f32x4 acc[8][4];
#pragma unroll
  for (int m = 0; m < 8; ++m)
#pragma unroll
    for (int n = 0; n < 4; ++n) acc[m][n] = (f32x4){0.f, 0.f, 0.f, 0.f};

  auto stageA = [&](int t, int h, int b) {
#pragma unroll
    for (int j = 0; j < 2; ++j) {
      int c = j * 512 + wave * 64 + lane;
      const __hip_bfloat16* g = A + (size_t)(c >> 2) * K + t * 64 + h * 32 + (c & 3) * 8;
      gload16(g, &lds[b * 32768 + h * 8192 + (j * 512 + wave * 64) * 8]);
    }
  };
  auto stageB = [&](int t, int h, int b) {
#pragma unroll
    for (int j = 0; j < 2; ++j) {
      int c = j * 512 + wave * 64 + lane;
      const __hip_bfloat16* g = B + (size_t)(c >> 2) * K + t * 64 + h * 32 + (c & 3) * 8;
      gload16(g, &lds[b * 32768 + 16384 + h * 8192 + (j * 512 + wave * 64) * 8]);
    }
  };
  auto ldA4 = [&](int h, int b, int mbase, bf16x8 (&af)[4]) {
#pragma unroll
    for (int m = 0; m < 4; ++m) {
      int row = wr * 128 + (mbase + m) * 16 + frow;
      af[m] = *(const bf16x8*)&lds[b * 32768 + h * 8192 + row * 32 + fk * 8];
    }
  };
  auto ldB4 = [&](int h, int b, bf16x8 (&bf)[4]) {
#pragma unroll
    for (int n = 0; n < 4; ++n) {
      int row = wc * 64 + n * 16 + frow;
      bf[n] = *(const bf16x8*)&lds[b * 32768 + 16384 + h * 8192 + row * 32 + fk * 8];
    }
  };
  auto mmh = [&](bf16x8 (&a)[4], bf16x8 (&bb)[4], int mbase) {
    __builtin_amdgcn_s_setprio(1);
#pragma unroll
    for (int m = 0; m < 4; ++m)
#pragma unroll
      for (int n = 0; n < 4; ++n)
        acc[mbase + m][n] =
            __builtin_amdgcn_mfma_f32_16x16x32_bf16(a[m], bb[n], acc[mbase + m][n], 0, 0, 0);
    __builtin_amdgcn_s_setprio(0);
    __builtin_amdgcn_sched_barrier(0);
  };

  stageA(0, 0, 0); stageB(0, 0, 0); stageA(0, 1, 0); stageB(0, 1, 0);

  for (int t = 0; t < NT - 1; ++t) {
    const int b = t & 1, nb = b ^ 1;
    SYNC_VM4();
    bf16x8 a[4], bb[4];
    ldA4(0, b, 0, a); ldB4(0, b, bb);
    stageA(t + 1, 0, nb);
    mmh(a, bb, 0);
    ldA4(0, b, 4, a);
    stageB(t + 1, 0, nb);
    mmh(a, bb, 4);
    SYNC_VM4();
    ldA4(1, b, 0, a); ldB4(1, b, bb);
    stageA(t + 1, 1, nb);
    mmh(a, bb, 0);
    ldA4(1, b, 4, a);
    stageB(t + 1, 1, nb);
    mmh(a, bb, 4);
  }
  {
    const int b = (NT - 1) & 1;
    SYNC_VM4();
    bf16x8 a[4], bb[4];
    ldA4(0, b, 0, a); ldB4(0, b, bb);
    mmh(a, bb, 0);
    ldA4(0, b, 4, a);
    mmh(a, bb, 4);
    SYNC_VM0();
    ldA4(1, b, 0, a); ldB4(1, b, bb);
    mmh(a, bb, 0);
    ldA4(1, b, 4, a);
    mmh(a, bb, 4);
  }

  float* Yt = Y + (size_t)(e * kCap + mt * 256) * kD + nt * 256;
#pragma unroll
  for (int m = 0; m < 8; ++m)
#pragma unroll
    for (int n = 0; n < 4; ++n)
#pragma unroll
      for (int r = 0; r < 4; ++r) {
        int row = wr * 128 + m * 16 + fk * 4 + r;
        int col = wc * 64 + n * 16 + frow;
        Yt[(size_t)row * kD + col] = acc[m][n][r];
      }
}

// ---------------- combine: out[t] = sum_k gate * y[slot] (deterministic gather) ----------------
__global__ __launch_bounds__(256)
void combine_kernel(const float* __restrict__ Y, const int* __restrict__ slot_of,
                    const float* __restrict__ gates, float* __restrict__ out) {
  int t = blockIdx.x;
  int dd = threadIdx.x * 4;
  int s0 = slot_of[2 * t], s1 = slot_of[2 * t + 1];
  float g0 = gates[2 * t], g1 = gates[2 * t + 1];
  float4 r = {0.f, 0.f, 0.f, 0.f};
  if (s0 >= 0) {
    float4 v = *(const float4*)(Y + (size_t)s0 * kD + dd);
    r.x += g0 * v.x; r.y += g0 * v.y; r.z += g0 * v.z; r.w += g0 * v.w;
  }
  if (s1 >= 0) {
    float4 v = *(const float4*)(Y + (size_t)s1 * kD + dd);
    r.x += g1 * v.x; r.y += g1 * v.y; r.z += g1 * v.z; r.w += g1 * v.w;
  }
  *(float4*)(out + (size_t)t * kD + dd) = r;
}

// ---------------- host launcher ----------------
extern "C" void kernel_launch(void* const* d_in, const int* in_sizes, int n_in,
                              void* d_out, int out_size, void* d_ws, size_t ws_size,
                              hipStream_t stream) {
  (void)in_sizes; (void)n_in; (void)out_size; (void)ws_size;
  const float* x  = (const float*)d_in[0];
  const float* rw = (const float*)d_in[1];
  const float* rb = (const float*)d_in[2];
  const float* w1 = (const float*)d_in[3];
  const float* w3 = (const float*)d_in[4];
  const float* w2 = (const float*)d_in[5];
  float* out = (float*)d_out;

  char* base = (char*)d_ws;
  size_t off = 0;
  auto alloc = [&](size_t bytes) -> char* {
    char* r = base + off;
    off += (bytes + 255) & ~(size_t)255;
    return r;
  };
  __hip_bfloat16* w1t = (__hip_bfloat16*)alloc((size_t)kE * kF * kD * 2);  // [E][F][D]
  __hip_bfloat16* w3t = (__hip_bfloat16*)alloc((size_t)kE * kF * kD * 2);  // [E][F][D]
  __hip_bfloat16* w2t = (__hip_bfloat16*)alloc((size_t)kE * kD * kF * 2);  // [E][D][F]
  __hip_bfloat16* buf = (__hip_bfloat16*)alloc((size_t)kECap * kD * 2);
  __hip_bfloat16* h   = (__hip_bfloat16*)alloc((size_t)kECap * kF * 2);
  float*          y   = (float*)alloc((size_t)kECap * kD * 4);
  int*   e_idx    = (int*)alloc((size_t)kN * 4);
  float* gates    = (float*)alloc((size_t)kN * 4);
  int*   pos      = (int*)alloc((size_t)kN * 4);
  int*   slot_of  = (int*)alloc((size_t)kN * 4);
  int*   token_of = (int*)alloc((size_t)kECap * 4);
  float* probs    = (float*)alloc((size_t)kT * 8 * 4);

  init_kernel<<<kECap / 256, 256, 0, stream>>>(token_of);
  transpose_kernel<<<dim3(kF / 32, kD / 32, kE), dim3(32, 8, 1), 0, stream>>>(w1, w1t, kD, kF);
  transpose_kernel<<<dim3(kF / 32, kD / 32, kE), dim3(32, 8, 1), 0, stream>>>(w3, w3t, kD, kF);
  transpose_kernel<<<dim3(kD / 32, kF / 32, kE), dim3(32, 8, 1), 0, stream>>>(w2, w2t, kF, kD);
  router_kernel<<<kT / 4, 256, 0, stream>>>(x, rw, rb, e_idx, gates, probs);
  aux_kernel<<<1, 1024, 0, stream>>>(probs, e_idx, out + (size_t)kT * kD);
  rank_kernel<<<kE, 256, 0, stream>>>(e_idx, pos);
  scatter_kernel<<<kN / 256, 256, 0, stream>>>(e_idx, pos, slot_of, token_of);
  gather_kernel<<<kECap, 64, 0, stream>>>(x, token_of, buf);
  gemm1_kernel<<<dim3(kF / 128, kCap / 256, kE), 512, 131072, stream>>>(buf, w1t, w3t, h);
  gemm2_kernel<<<dim3(kD / 256, kCap / 256, kE), 512, 131072, stream>>>(h, w2t, y);
  combine_kernel<<<kT, 256, 0, stream>>>(y, slot_of, gates, out);
}

// Round 5
// 608.193 us; speedup vs baseline: 3.1079x; 1.0555x over previous
//
#include <hip/hip_runtime.h>
#include <hip/hip_bf16.h>
#include <math.h>

// ---------------- problem constants ----------------
constexpr int kT    = 8192;          // tokens (4*2048)
constexpr int kD    = 1024;          // d_model
constexpr int kF    = 4096;          // d_ff
constexpr int kE    = 8;             // experts
constexpr int kN    = kT * 2;        // top-k dispatch count = 16384
constexpr int kCap  = 2048;          // ceil(1.0 * 16384 / 8)
constexpr int kECap = kE * kCap;     // 16384

typedef __attribute__((ext_vector_type(8))) short bf16x8;   // 8 bf16 (4 VGPR) MFMA A/B frag
typedef __attribute__((ext_vector_type(4))) float f32x4;    // MFMA C/D frag

// async global->LDS, 16B per lane; LDS dst must be wave-uniform (HW adds lane*16)
__device__ __forceinline__ void gload16(const __hip_bfloat16* g, __hip_bfloat16* l) {
  auto gp = (const __attribute__((address_space(1))) __hip_bfloat16*)g;
  auto lp = (__attribute__((address_space(3))) __hip_bfloat16*)l;
  __builtin_amdgcn_global_load_lds((const __attribute__((address_space(1))) void*)gp,
                                   (__attribute__((address_space(3))) void*)lp,
                                   16, 0, 0);
}

// sync points: pin schedule, counted vmcnt, raw barrier (no compiler drain)
#define SYNC_VM(N) do { __builtin_amdgcn_sched_barrier(0); \
  asm volatile("s_waitcnt vmcnt(" #N ")" ::: "memory"); \
  __builtin_amdgcn_s_barrier(); \
  asm volatile("" ::: "memory"); } while (0)

// ---------------- init: token_of = -1 ----------------
__global__ void init_kernel(int* token_of) {
  int i = blockIdx.x * 256 + threadIdx.x;
  if (i < kECap) token_of[i] = -1;
}

// ---------------- transpose+convert: src [E][R][C] f32 -> dst [E][C][R] bf16 ----------------
__global__ __launch_bounds__(256)
void transpose_kernel(const float* __restrict__ src, __hip_bfloat16* __restrict__ dst,
                      int R, int C) {
  __shared__ float tile[32][33];
  const size_t mat = (size_t)R * C;
  const float* s = src + (size_t)blockIdx.z * mat;
  __hip_bfloat16* d = dst + (size_t)blockIdx.z * mat;
  int c0 = blockIdx.x * 32, r0 = blockIdx.y * 32;
  int tx = threadIdx.x, ty = threadIdx.y;
#pragma unroll
  for (int i = 0; i < 32; i += 8)
    tile[ty + i][tx] = s[(size_t)(r0 + ty + i) * C + (c0 + tx)];
  __syncthreads();
#pragma unroll
  for (int i = 0; i < 32; i += 8)
    d[(size_t)(c0 + ty + i) * R + (r0 + tx)] = __float2bfloat16(tile[tx][ty + i]);
}

// ---------------- router: fp32 logits, softmax, top-2, gates; probs -> ws (NO atomics) ----------------
__global__ __launch_bounds__(256)
void router_kernel(const float* __restrict__ x, const float* __restrict__ rw,
                   const float* __restrict__ rb, int* __restrict__ e_idx,
                   float* __restrict__ gates, float* __restrict__ probs_out) {
  int t = blockIdx.x * 4 + (threadIdx.x >> 6);
  int lane = threadIdx.x & 63;
  const float* xr = x + (size_t)t * kD;
  float acc[8];
#pragma unroll
  for (int e = 0; e < 8; ++e) acc[e] = 0.f;
  for (int i = 0; i < kD / 64; ++i) {
    int dd = i * 64 + lane;
    float xv = xr[dd];
    const float4* w4 = (const float4*)(rw + (size_t)dd * 8);
    float4 wa = w4[0], wb = w4[1];
    acc[0] += xv * wa.x; acc[1] += xv * wa.y; acc[2] += xv * wa.z; acc[3] += xv * wa.w;
    acc[4] += xv * wb.x; acc[5] += xv * wb.y; acc[6] += xv * wb.z; acc[7] += xv * wb.w;
  }
#pragma unroll
  for (int off = 32; off >= 1; off >>= 1) {
#pragma unroll
    for (int e = 0; e < 8; ++e) acc[e] += __shfl_xor(acc[e], off);
  }
  if (lane == 0) {
    float l[8], m = -1e30f;
#pragma unroll
    for (int e = 0; e < 8; ++e) { l[e] = acc[e] + rb[e]; m = fmaxf(m, l[e]); }
    float p[8], s = 0.f;
#pragma unroll
    for (int e = 0; e < 8; ++e) { p[e] = __expf(l[e] - m); s += p[e]; }
    float inv = 1.f / s;
#pragma unroll
    for (int e = 0; e < 8; ++e) p[e] *= inv;
    int i1 = 0;
#pragma unroll
    for (int e = 1; e < 8; ++e) if (p[e] > p[i1]) i1 = e;   // strict >: ties -> lowest idx
    int i2 = (i1 == 0) ? 1 : 0;
#pragma unroll
    for (int e = 0; e < 8; ++e) if (e != i1 && e != i2 && p[e] > p[i2]) i2 = e;
    float den = fmaxf(p[i1] + p[i2], 1e-9f);
    e_idx[2 * t] = i1; e_idx[2 * t + 1] = i2;
    gates[2 * t] = p[i1] / den; gates[2 * t + 1] = p[i2] / den;
    float4* po = (float4*)(probs_out + (size_t)t * 8);
    po[0] = make_float4(p[0], p[1], p[2], p[3]);
    po[1] = make_float4(p[4], p[5], p[6], p[7]);
  }
}

// ---------------- aux: importance/load reduction + aux loss (single block) ----------------
__global__ __launch_bounds__(1024)
void aux_kernel(const float* __restrict__ probs, const int* __restrict__ e_idx,
                float* __restrict__ aux_out) {
  int tid = threadIdx.x, lane = tid & 63, wave = tid >> 6;
  float imp[8];
  int cnt[8];
#pragma unroll
  for (int e = 0; e < 8; ++e) { imp[e] = 0.f; cnt[e] = 0; }
  for (int t = tid; t < kT; t += 1024) {
    const float4* p4 = (const float4*)(probs + (size_t)t * 8);
    float4 a = p4[0], b = p4[1];
    imp[0] += a.x; imp[1] += a.y; imp[2] += a.z; imp[3] += a.w;
    imp[4] += b.x; imp[5] += b.y; imp[6] += b.z; imp[7] += b.w;
    ++cnt[e_idx[2 * t] & 7];
  }
#pragma unroll
  for (int off = 32; off >= 1; off >>= 1) {
#pragma unroll
    for (int e = 0; e < 8; ++e) {
      imp[e] += __shfl_xor(imp[e], off);
      cnt[e] += __shfl_xor(cnt[e], off);
    }
  }
  __shared__ float simp[16][8];
  __shared__ int scnt[16][8];
  if (lane == 0) {
#pragma unroll
    for (int e = 0; e < 8; ++e) { simp[wave][e] = imp[e]; scnt[wave][e] = cnt[e]; }
  }
  __syncthreads();
  if (tid == 0) {
    float lb = 0.f;
    for (int e = 0; e < 8; ++e) {
      float I = 0.f; int C = 0;
      for (int w = 0; w < 16; ++w) { I += simp[w][e]; C += scnt[w][e]; }
      lb += (I / (float)kT) * ((float)C / (float)kT);
    }
    aux_out[0] = 0.01f * lb * (float)kE;   // Z_COEF == 0
  }
}

// ---------------- stable rank within expert (counting-sort order) ----------------
__global__ __launch_bounds__(256)
void rank_kernel(const int* __restrict__ e_idx, int* __restrict__ pos) {
  int e = blockIdx.x;                 // one block per expert
  __shared__ int wave_sum[4];
  __shared__ int running;
  int tid = threadIdx.x, lane = tid & 63, wave = tid >> 6;
  if (tid == 0) running = 0;
  __syncthreads();
  for (int base = 0; base < kN; base += 256) {
    int i = base + tid;
    bool f = (e_idx[i] == e);
    unsigned long long m = __ballot(f);
    int wpre = __popcll(m & ((1ull << lane) - 1ull));
    if (lane == 0) wave_sum[wave] = __popcll(m);
    __syncthreads();
    int woff = 0;
    for (int w = 0; w < wave; ++w) woff += wave_sum[w];
    int r = running;
    if (f) pos[i] = r + woff + wpre;
    __syncthreads();
    if (tid == 0) running = r + wave_sum[0] + wave_sum[1] + wave_sum[2] + wave_sum[3];
    __syncthreads();
  }
}

// ---------------- scatter: slot assignment + inverse map ----------------
__global__ __launch_bounds__(256)
void scatter_kernel(const int* __restrict__ e_idx, const int* __restrict__ pos,
                    int* __restrict__ slot_of, int* __restrict__ token_of) {
  int i = blockIdx.x * 256 + threadIdx.x;
  if (i >= kN) return;
  int p = pos[i];
  if (p < kCap) {
    int slot = e_idx[i] * kCap + p;
    slot_of[i] = slot;
    token_of[slot] = i >> 1;
  } else {
    slot_of[i] = -1;                  // dropped (over capacity)
  }
}

// ---------------- gather: x rows -> bf16 expert buffer (zeros for unused slots) ----------------
struct __attribute__((aligned(8))) bf16x4s { __hip_bfloat16 v[4]; };

__global__ __launch_bounds__(64)
void gather_kernel(const float* __restrict__ x, const int* __restrict__ token_of,
                   __hip_bfloat16* __restrict__ buf) {
  int slot = blockIdx.x, lane = threadIdx.x;
  int t = token_of[slot];
  __hip_bfloat16* br = buf + (size_t)slot * kD;
  if (t >= 0) {
    const float* xr = x + (size_t)t * kD;
#pragma unroll
    for (int j = 0; j < 4; ++j) {
      int dd = (j * 64 + lane) * 4;
      float4 v = *(const float4*)(xr + dd);
      bf16x4s o;
      o.v[0] = __float2bfloat16(v.x); o.v[1] = __float2bfloat16(v.y);
      o.v[2] = __float2bfloat16(v.z); o.v[3] = __float2bfloat16(v.w);
      *(bf16x4s*)(br + dd) = o;
    }
  } else {
    bf16x4s z;
    z.v[0] = z.v[1] = z.v[2] = z.v[3] = __float2bfloat16(0.f);
#pragma unroll
    for (int j = 0; j < 4; ++j) *(bf16x4s*)(br + (j * 64 + lane) * 4) = z;
  }
}

// ================= GEMM1: h = silu(buf@w1) * (buf@w3) =================
// tile 256M x 128F, BK=64, 8 waves 4M x 2N, wave 64x64 dual (U,V)
// LDS/buf: A[256][64] swz (32KB) | B[w1 128 | w3 128][64] swz (32KB); 2 buf = 128KB
// swizzle: LDS slot s holds global col-chunk s^(row&7); reads use same XOR (2 lanes/bank)
// phases: ph0 = U-MFMA (needs A(t), B1(t)), ph1 = V-MFMA (needs B3(t))
// per-tile issue [A(4), B1(2), B3(2)] staged by reader waves only:
//   SYNC vmcnt(2) (B3 in flight), MID vmcnt(4) (next A in flight) — never 0 in steady state
__global__ __launch_bounds__(512, 2)
void gemm1_kernel(const __hip_bfloat16* __restrict__ Abase,
                  const __hip_bfloat16* __restrict__ W1t,
                  const __hip_bfloat16* __restrict__ W3t,
                  __hip_bfloat16* __restrict__ H) {
  constexpr int K = kD;             // 1024
  constexpr int NT = K / 64;        // 16 K-tiles
  const int e = blockIdx.z, mt = blockIdx.y, ft = blockIdx.x;
  const int tid = threadIdx.x, lane = tid & 63, wave = tid >> 6;
  const int wr = wave >> 1, wc = wave & 1;   // 4M x 2N
  const int frow = lane & 15, fk = lane >> 4;

  const __hip_bfloat16* A  = Abase + (size_t)(e * kCap + mt * 256) * K;
  const __hip_bfloat16* B1 = W1t + ((size_t)e * kF + ft * 128) * K;
  const __hip_bfloat16* B3 = W3t + ((size_t)e * kF + ft * 128) * K;

  extern __shared__ __hip_bfloat16 lds[];   // 2 x 32768 elems

  f32x4 accU[4][4], accV[4][4];
#pragma unroll
  for (int m = 0; m < 4; ++m)
#pragma unroll
    for (int n = 0; n < 4; ++n) {
      accU[m][n] = (f32x4){0.f, 0.f, 0.f, 0.f};
      accV[m][n] = (f32x4){0.f, 0.f, 0.f, 0.f};
    }

  // ---- staging (reader-aligned). chunk c in a 512-chunk quarter: rl=c>>3, slot=c&7,
  // global col-chunk = slot ^ (rl&7); LDS linear at quarterbase + c*16B (wave-uniform+lane*16)
  auto stageA = [&](int t, int b) {        // quarter wr (rows wr*64..), staged by waves (wr,*)
#pragma unroll
    for (int j = 0; j < 4; ++j) {
      int c = j * 128 + wc * 64 + lane;
      int rl = c >> 3, s = c & 7;
      const __hip_bfloat16* g = A + (size_t)(wr * 64 + rl) * K + t * 64 + (s ^ (rl & 7)) * 8;
      gload16(g, &lds[b * 32768 + wr * 4096 + (j * 128 + wc * 64) * 8]);
    }
  };
  auto stageB1 = [&](int t, int b) {       // w1 quarter wc, staged by waves (*,wc)
#pragma unroll
    for (int j = 0; j < 2; ++j) {
      int c = j * 256 + wr * 64 + lane;
      int rl = c >> 3, s = c & 7;
      const __hip_bfloat16* g = B1 + (size_t)(wc * 64 + rl) * K + t * 64 + (s ^ (rl & 7)) * 8;
      gload16(g, &lds[b * 32768 + 16384 + wc * 4096 + (j * 256 + wr * 64) * 8]);
    }
  };
  auto stageB3 = [&](int t, int b) {       // w3 quarter wc (LDS rows 128+)
#pragma unroll
    for (int j = 0; j < 2; ++j) {
      int c = j * 256 + wr * 64 + lane;
      int rl = c >> 3, s = c & 7;
      const __hip_bfloat16* g = B3 + (size_t)(wc * 64 + rl) * K + t * 64 + (s ^ (rl & 7)) * 8;
      gload16(g, &lds[b * 32768 + 16384 + 8192 + wc * 4096 + (j * 256 + wr * 64) * 8]);
    }
  };
  // phase: 32 MFMA; A frags loaded once (ph0), reused in ph1
  auto phase = [&](int b, f32x4 (&ac)[4][4], bf16x8 (&af)[4][2], int broff, bool loadA) {
    if (loadA) {
#pragma unroll
      for (int m = 0; m < 4; ++m)
#pragma unroll
        for (int h = 0; h < 2; ++h) {
          int row = wr * 64 + m * 16 + frow;
          af[m][h] = *(const bf16x8*)&lds[b * 32768 + row * 64 + ((h * 4 + fk) ^ (row & 7)) * 8];
        }
    }
    bf16x8 bf[4][2];
#pragma unroll
    for (int n = 0; n < 4; ++n)
#pragma unroll
      for (int h = 0; h < 2; ++h) {
        int row = broff + wc * 64 + n * 16 + frow;
        bf[n][h] = *(const bf16x8*)&lds[b * 32768 + 16384 + row * 64 + ((h * 4 + fk) ^ (row & 7)) * 8];
      }
    __builtin_amdgcn_s_setprio(1);
#pragma unroll
    for (int m = 0; m < 4; ++m)
#pragma unroll
      for (int n = 0; n < 4; ++n)
#pragma unroll
        for (int h = 0; h < 2; ++h)
          ac[m][n] = __builtin_amdgcn_mfma_f32_16x16x32_bf16(af[m][h], bf[n][h], ac[m][n], 0, 0, 0);
    __builtin_amdgcn_s_setprio(0);
    __builtin_amdgcn_sched_barrier(0);
  };

  // prologue: tile 0, order [A, B1, B3]
  stageA(0, 0); stageB1(0, 0); stageB3(0, 0);

  for (int t = 0; t < NT; ++t) {
    const int b = t & 1, nb = b ^ 1;
    const bool nx = (t + 1 < NT);
    SYNC_VM(2);                              // A(t), B1(t) landed; B3(t) may be in flight
    if (nx) stageA(t + 1, nb);
    bf16x8 af[4][2];
    phase(b, accU, af, 0, true);             // U
    if (nx) { SYNC_VM(4); } else { SYNC_VM(0); }   // B3(t) landed
    if (nx) stageB1(t + 1, nb);
    phase(b, accV, af, 128, false);          // V
    if (nx) stageB3(t + 1, nb);
  }

  // epilogue: h = silu(u) * v
  __hip_bfloat16* Ht = H + (size_t)(e * kCap + mt * 256) * kF + ft * 128;
#pragma unroll
  for (int m = 0; m < 4; ++m)
#pragma unroll
    for (int n = 0; n < 4; ++n)
#pragma unroll
      for (int r = 0; r < 4; ++r) {
        int row = wr * 64 + m * 16 + fk * 4 + r;   // C/D: col=lane&15, row=(lane>>4)*4+reg
        int col = wc * 64 + n * 16 + frow;
        float u = accU[m][n][r], v = accV[m][n][r];
        float hval = (u / (1.f + __expf(-u))) * v;
        Ht[(size_t)row * kF + col] = __float2bfloat16(hval);
      }
}

// ================= GEMM2: y = h @ w2 =================
// tile 256M x 256N, BK=64, 8 waves 2M x 4N, wave 128x64
// LDS/buf: A[256][64] swz | B[256][64] swz; 2 buf = 128KB
// phases: ph0 = m-frags 0-3 (A quarter 2wr), ph1 = m-frags 4-7 (A quarter 2wr+1)
// per-tile issue [B(4), A0(2), A1(2)] reader-aligned; SYNC vmcnt(2), MID vmcnt(4)
__global__ __launch_bounds__(512, 2)
void gemm2_kernel(const __hip_bfloat16* __restrict__ Hbase,
                  const __hip_bfloat16* __restrict__ W2t,
                  float* __restrict__ Y) {
  constexpr int K = kF;             // 4096
  constexpr int NT = K / 64;        // 64 K-tiles
  const int e = blockIdx.z, mt = blockIdx.y, nt = blockIdx.x;
  const int tid = threadIdx.x, lane = tid & 63, wave = tid >> 6;
  const int wr = wave >> 2, wc = wave & 3;   // 2M x 4N
  const int frow = lane & 15, fk = lane >> 4;

  const __hip_bfloat16* A = Hbase + (size_t)(e * kCap + mt * 256) * K;
  const __hip_bfloat16* B = W2t + ((size_t)e * kD + nt * 256) * K;

  extern __shared__ __hip_bfloat16 lds[];

  f32x4 acc[2][4][4];
#pragma unroll
  for (int p = 0; p < 2; ++p)
#pragma unroll
    for (int m = 0; m < 4; ++m)
#pragma unroll
      for (int n = 0; n < 4; ++n) acc[p][m][n] = (f32x4){0.f, 0.f, 0.f, 0.f};

  auto stageB = [&](int t, int b) {        // B quarter wc, staged by waves (0,wc),(1,wc)
#pragma unroll
    for (int j = 0; j < 4; ++j) {
      int c = j * 128 + wr * 64 + lane;
      int rl = c >> 3, s = c & 7;
      const __hip_bfloat16* g = B + (size_t)(wc * 64 + rl) * K + t * 64 + (s ^ (rl & 7)) * 8;
      gload16(g, &lds[b * 32768 + 16384 + wc * 4096 + (j * 128 + wr * 64) * 8]);
    }
  };
  auto stageA = [&](int t, int p, int b) { // A quarter 2wr+p, staged by waves (wr,*)
    int q = 2 * wr + p;
#pragma unroll
    for (int j = 0; j < 2; ++j) {
      int c = j * 256 + wc * 64 + lane;
      int rl = c >> 3, s = c & 7;
      const __hip_bfloat16* g = A + (size_t)(q * 64 + rl) * K + t * 64 + (s ^ (rl & 7)) * 8;
      gload16(g, &lds[b * 32768 + q * 4096 + (j * 256 + wc * 64) * 8]);
    }
  };
  // phase p: A rows wr*128 + p*64 .. +64; B frags loaded once (ph0), reused ph1
  auto phase = [&](int b, int p, f32x4 (&ac)[4][4], bf16x8 (&bf)[4][2], bool loadB) {
    bf16x8 a[4][2];
#pragma unroll
    for (int m = 0; m < 4; ++m)
#pragma unroll
      for (int h = 0; h < 2; ++h) {
        int row = wr * 128 + p * 64 + m * 16 + frow;
        a[m][h] = *(const bf16x8*)&lds[b * 32768 + row * 64 + ((h * 4 + fk) ^ (row & 7)) * 8];
      }
    if (loadB) {
#pragma unroll
      for (int n = 0; n < 4; ++n)
#pragma unroll
        for (int h = 0; h < 2; ++h) {
          int row = wc * 64 + n * 16 + frow;
          bf[n][h] = *(const bf16x8*)&lds[b * 32768 + 16384 + row * 64 + ((h * 4 + fk) ^ (row & 7)) * 8];
        }
    }
    __builtin_amdgcn_s_setprio(1);
#pragma unroll
    for (int m = 0; m < 4; ++m)
#pragma unroll
      for (int n = 0; n < 4; ++n)
#pragma unroll
        for (int h = 0; h < 2; ++h)
          ac[m][n] = __builtin_amdgcn_mfma_f32_16x16x32_bf16(a[m][h], bf[n][h], ac[m][n], 0, 0, 0);
    __builtin_amdgcn_s_setprio(0);
    __builtin_amdgcn_sched_barrier(0);
  };

  stageB(0, 0); stageA(0, 0, 0); stageA(0, 1, 0);

  for (int t = 0; t < NT; ++t) {
    const int b = t & 1, nb = b ^ 1;
    const bool nx = (t + 1 < NT);
    SYNC_VM(2);                              // B(t), A0(t) landed; A1(t) may be in flight
    if (nx) stageB(t + 1, nb);
    bf16x8 bf[4][2];
    phase(b, 0, acc[0], bf, true);
    if (nx) { SYNC_VM(4); } else { SYNC_VM(0); }   // A1(t) landed
    if (nx) stageA(t + 1, 0, nb);
    phase(b, 1, acc[1], bf, false);
    if (nx) stageA(t + 1, 1, nb);
  }

  float* Yt = Y + (size_t)(e * kCap + mt * 256) * kD + nt * 256;
#pragma unroll
  for (int p = 0; p < 2; ++p)
#pragma unroll
    for (int m = 0; m < 4; ++m)
#pragma unroll
      for (int n = 0; n < 4; ++n)
#pragma unroll
        for (int r = 0; r < 4; ++r) {
          int row = wr * 128 + p * 64 + m * 16 + fk * 4 + r;
          int col = wc * 64 + n * 16 + frow;
          Yt[(size_t)row * kD + col] = acc[p][m][n][r];
        }
}

// ---------------- combine: out[t] = sum_k gate * y[slot] (deterministic gather) ----------------
__global__ __launch_bounds__(256)
void combine_kernel(const float* __restrict__ Y, const int* __restrict__ slot_of,
                    const float* __restrict__ gates, float* __restrict__ out) {
  int t = blockIdx.x;
  int dd = threadIdx.x * 4;
  int s0 = slot_of[2 * t], s1 = slot_of[2 * t + 1];
  float g0 = gates[2 * t], g1 = gates[2 * t + 1];
  float4 r = {0.f, 0.f, 0.f, 0.f};
  if (s0 >= 0) {
    float4 v = *(const float4*)(Y + (size_t)s0 * kD + dd);
    r.x += g0 * v.x; r.y += g0 * v.y; r.z += g0 * v.z; r.w += g0 * v.w;
  }
  if (s1 >= 0) {
    float4 v = *(const float4*)(Y + (size_t)s1 * kD + dd);
    r.x += g1 * v.x; r.y += g1 * v.y; r.z += g1 * v.z; r.w += g1 * v.w;
  }
  *(float4*)(out + (size_t)t * kD + dd) = r;
}

// ---------------- host launcher ----------------
extern "C" void kernel_launch(void* const* d_in, const int* in_sizes, int n_in,
                              void* d_out, int out_size, void* d_ws, size_t ws_size,
                              hipStream_t stream) {
  (void)in_sizes; (void)n_in; (void)out_size; (void)ws_size;
  const float* x  = (const float*)d_in[0];
  const float* rw = (const float*)d_in[1];
  const float* rb = (const float*)d_in[2];
  const float* w1 = (const float*)d_in[3];
  const float* w3 = (const float*)d_in[4];
  const float* w2 = (const float*)d_in[5];
  float* out = (float*)d_out;

  char* base = (char*)d_ws;
  size_t off = 0;
  auto alloc = [&](size_t bytes) -> char* {
    char* r = base + off;
    off += (bytes + 255) & ~(size_t)255;
    return r;
  };
  __hip_bfloat16* w1t = (__hip_bfloat16*)alloc((size_t)kE * kF * kD * 2);  // [E][F][D]
  __hip_bfloat16* w3t = (__hip_bfloat16*)alloc((size_t)kE * kF * kD * 2);  // [E][F][D]
  __hip_bfloat16* w2t = (__hip_bfloat16*)alloc((size_t)kE * kD * kF * 2);  // [E][D][F]
  __hip_bfloat16* buf = (__hip_bfloat16*)alloc((size_t)kECap * kD * 2);
  __hip_bfloat16* h   = (__hip_bfloat16*)alloc((size_t)kECap * kF * 2);
  float*          y   = (float*)alloc((size_t)kECap * kD * 4);
  int*   e_idx    = (int*)alloc((size_t)kN * 4);
  float* gates    = (float*)alloc((size_t)kN * 4);
  int*   pos      = (int*)alloc((size_t)kN * 4);
  int*   slot_of  = (int*)alloc((size_t)kN * 4);
  int*   token_of = (int*)alloc((size_t)kECap * 4);
  float* probs    = (float*)alloc((size_t)kT * 8 * 4);

  init_kernel<<<kECap / 256, 256, 0, stream>>>(token_of);
  transpose_kernel<<<dim3(kF / 32, kD / 32, kE), dim3(32, 8, 1), 0, stream>>>(w1, w1t, kD, kF);
  transpose_kernel<<<dim3(kF / 32, kD / 32, kE), dim3(32, 8, 1), 0, stream>>>(w3, w3t, kD, kF);
  transpose_kernel<<<dim3(kD / 32, kF / 32, kE), dim3(32, 8, 1), 0, stream>>>(w2, w2t, kF, kD);
  router_kernel<<<kT / 4, 256, 0, stream>>>(x, rw, rb, e_idx, gates, probs);
  aux_kernel<<<1, 1024, 0, stream>>>(probs, e_idx, out + (size_t)kT * kD);
  rank_kernel<<<kE, 256, 0, stream>>>(e_idx, pos);
  scatter_kernel<<<kN / 256, 256, 0, stream>>>(e_idx, pos, slot_of, token_of);
  gather_kernel<<<kECap, 64, 0, stream>>>(x, token_of, buf);
  gemm1_kernel<<<dim3(kF / 128, kCap / 256, kE), 512, 131072, stream>>>(buf, w1t, w3t, h);
  gemm2_kernel<<<dim3(kD / 256, kCap / 256, kE), 512, 131072, stream>>>(h, w2t, y);
  combine_kernel<<<kT, 256, 0, stream>>>(y, slot_of, gates, out);
}